// Round 14
// baseline (824.290 us; speedup 1.0000x reference)
//
#include <hip/hip_runtime.h>
#include <stdint.h>

typedef unsigned short u16;
typedef unsigned int   u32;
typedef float  f32x4  __attribute__((ext_vector_type(4)));
typedef __bf16 bf16x8 __attribute__((ext_vector_type(8)));
typedef u16    u16x4  __attribute__((ext_vector_type(4)));
typedef u16    u16x8  __attribute__((ext_vector_type(8)));

#define T_N     2048
#define D_N     4096
#define H_N     128
#define P_N     64
#define G_N     8
#define NS_N    128
#define INTER_N 8192
#define CONVD_N 10240
#define PROJ_N  18560
#define NGEMM_N 18432
#define NC_N    16

__device__ __forceinline__ float bf2f(u16 u){ u32 x = ((u32)u) << 16; return __builtin_bit_cast(float, x); }
__device__ __forceinline__ u16 f2bf(float f){
  u32 u = __builtin_bit_cast(u32, f);
  u += 0x7FFFu + ((u >> 16) & 1u);
  return (u16)(u >> 16);
}

__device__ __forceinline__ void gld_lds16(const void* g, void* lds){
  __builtin_amdgcn_global_load_lds(
      (const __attribute__((address_space(1))) void*)(uintptr_t)g,
      (__attribute__((address_space(3))) void*)(u32)(uintptr_t)lds,
      16, 0, 0);
}

// ---------------- add + RMSNorm ----------------
__global__ __launch_bounds__(256)
void k_addnorm(const float* __restrict__ hin, const float* __restrict__ rin,
               const float* __restrict__ nw, float* __restrict__ resid,
               u16* __restrict__ hs16, float* __restrict__ rstd){
  __shared__ float red[4];
  const int row = blockIdx.x, tid = threadIdx.x;
  const size_t rb = (size_t)row * D_N;
  f32x4 s[4];
  float ss = 0.f;
  #pragma unroll
  for (int i = 0; i < 4; ++i){
    int c4 = tid + i*256;
    f32x4 a = *(const f32x4*)&hin[rb + (size_t)c4*4];
    f32x4 b = *(const f32x4*)&rin[rb + (size_t)c4*4];
    s[i] = a + b;
    *(f32x4*)&resid[rb + (size_t)c4*4] = s[i];
    ss += s[i][0]*s[i][0] + s[i][1]*s[i][1] + s[i][2]*s[i][2] + s[i][3]*s[i][3];
  }
  #pragma unroll
  for (int o = 32; o > 0; o >>= 1) ss += __shfl_down(ss, o, 64);
  if ((tid & 63) == 0) red[tid >> 6] = ss;
  __syncthreads();
  float tot = (red[0] + red[1]) + (red[2] + red[3]);
  float rs = rsqrtf(tot / (float)D_N + 1e-5f);
  if (tid == 0) rstd[row] = rs;
  #pragma unroll
  for (int i = 0; i < 4; ++i){
    int c4 = tid + i*256;
    f32x4 w = *(const f32x4*)&nw[(size_t)c4*4];
    u16x4 o = { f2bf(s[i][0]*rs*w[0]), f2bf(s[i][1]*rs*w[1]),
                f2bf(s[i][2]*rs*w[2]), f2bf(s[i][3]*rs*w[3]) };
    *(u16x4*)&hs16[rb + (size_t)c4*4] = o;
  }
}

// ---------------- fp32 -> bf16 conversion (both weights in one launch) ----------------
__global__ void k_cvt2(const float* __restrict__ in1, u16* __restrict__ out1, size_t n4a,
                       const float* __restrict__ in2, u16* __restrict__ out2, size_t n4b){
  size_t i = (size_t)blockIdx.x * blockDim.x + threadIdx.x;
  size_t stride = (size_t)gridDim.x * blockDim.x;
  size_t tot = n4a + n4b;
  for (; i < tot; i += stride){
    const float* in = (i < n4a) ? in1 : in2;
    u16* out = (i < n4a) ? out1 : out2;
    size_t j = (i < n4a) ? i : i - n4a;
    f32x4 v = *(const f32x4*)&in[j*4];
    u16x4 o = { f2bf(v[0]), f2bf(v[1]), f2bf(v[2]), f2bf(v[3]) };
    *(u16x4*)&out[j*4] = o;
  }
}

// ---------------- Wn[d][h] = in_proj_w[18432+h][d] * norm_w[d]  (LDS transpose) ----------
__global__ __launch_bounds__(256)
void k_wdt(const float* __restrict__ W, const float* __restrict__ nw,
           float* __restrict__ Wn){
  __shared__ float lt[32][133];
  const int tid = threadIdx.x;
  const int d0 = blockIdx.x * 32;
  #pragma unroll
  for (int i = 0; i < 16; ++i){
    int h = i*8 + (tid >> 5);
    int d = tid & 31;
    lt[d][h] = W[(size_t)(INTER_N + CONVD_N + h)*D_N + d0 + d];
  }
  __syncthreads();
  #pragma unroll
  for (int i = 0; i < 4; ++i){
    int d = i*8 + (tid >> 5);
    int h4 = (tid & 31) * 4;
    float nwv = nw[d0 + d];
    f32x4 v = { lt[d][h4]*nwv, lt[d][h4+1]*nwv, lt[d][h4+2]*nwv, lt[d][h4+3]*nwv };
    *(f32x4*)&Wn[(size_t)(d0 + d)*128 + h4] = v;
  }
}

// ---------------- fp32 dt GEMM, split-K x8 (f32x4 LDS reads) ----------------
__global__ __launch_bounds__(256)
void k_dtgemm(const float* __restrict__ resid, const float* __restrict__ Wn,
              float* __restrict__ dtpart){
  __shared__ float lhs[16*128];
  const int tid = threadIdx.x;
  const int tb = blockIdx.x >> 3, ks = blockIdx.x & 7;
  const int t0 = tb * 16;
  const int k0 = ks * (D_N / 8);
  const int hcol = tid & 127, rh = tid >> 7;
  float acc[8] = {0,0,0,0,0,0,0,0};
  for (int kt = k0; kt < k0 + D_N/8; kt += 128){
    __syncthreads();
    #pragma unroll
    for (int it = 0; it < 2; ++it){
      int idx = it*256 + tid;
      int rr = idx >> 5, c4 = idx & 31;
      *(f32x4*)&lhs[rr*128 + c4*4] = *(const f32x4*)&resid[(size_t)(t0+rr)*D_N + kt + c4*4];
    }
    __syncthreads();
    #pragma unroll 4
    for (int kk4 = 0; kk4 < 32; ++kk4){
      f32x4 w4;
      #pragma unroll
      for (int j = 0; j < 4; ++j) w4[j] = Wn[(size_t)(kt + kk4*4 + j)*128 + hcol];
      #pragma unroll
      for (int j = 0; j < 8; ++j){
        f32x4 lv = *(const f32x4*)&lhs[(rh*8 + j)*128 + kk4*4];
        acc[j] += lv[0]*w4[0] + lv[1]*w4[1] + lv[2]*w4[2] + lv[3]*w4[3];
      }
    }
  }
  #pragma unroll
  for (int j = 0; j < 8; ++j){
    int t = t0 + rh*8 + j;
    dtpart[((size_t)ks*T_N + t)*128 + hcol] = acc[j];
  }
}

// ---------------- dt sum+softplus (fully parallel) ----------------
__global__ __launch_bounds__(256)
void k_dtsum(const float* __restrict__ dtpart, const float* __restrict__ rstd,
             const float* __restrict__ dt_bias, const float* __restrict__ A_log,
             float* __restrict__ dtv, float* __restrict__ dta){
  int idx = blockIdx.x*256 + threadIdx.x;       // T*128
  int t = idx >> 7, h = idx & 127;
  float s = 0.f;
  #pragma unroll
  for (int k = 0; k < 8; ++k) s += dtpart[((size_t)k*T_N + t)*128 + h];
  float x = s * rstd[t] + dt_bias[h];
  float dv = (x > 20.f) ? x : log1pf(expf(x));
  dtv[idx] = dv;
  dta[idx] = dv * (-expf(A_log[h]));
}

// ---------------- dt cumsum per chunk ------------------------
__global__ void k_dtprep(const float* __restrict__ dta, float* __restrict__ cum,
                         float* __restrict__ cumend, float* __restrict__ dec){
  int c = blockIdx.x, h = threadIdx.x;
  float cm = 0.f;
  for (int q = 0; q < 128; ++q){
    size_t i = (size_t)(c*128 + q)*128 + h;
    cm += dta[i];
    cum[i] = cm;
  }
  cumend[c*128 + h] = cm;
  dec[c*128 + h] = expf(cm);
}

// ========== 128 x (NF*32) merged-4-phase bf16 GEMM, wave tile 64 x (NF*16) ==========
// (in_proj; unchanged — characterized at ~54% MfmaUtil, LDS-read/MFMA serialization bound)
#define STA(BUF,HH,KT) gld_lds16(pA + (size_t)((HH)*32)*K + (size_t)(KT)*64, shb + (BUF)*BSZ + (HH)*4096 + tid*16)
#define STB(BUF,HH,KT) gld_lds16(pB + (size_t)((HH)*32)*K + (size_t)(KT)*64, shb + (BUF)*BSZ + 16384 + (HH)*4096 + tid*16)
#define VMWN do { asm volatile("s_waitcnt vmcnt(%0)" :: "n"(NF) : "memory"); __builtin_amdgcn_sched_barrier(0); } while(0)
#define RDA4(BUF, MOFF)                                                                 \
    bf16x8 a0 = *(const bf16x8*)(shb + (BUF)*BSZ + rdA + (MOFF)*2048 + sA0);            \
    bf16x8 a1 = *(const bf16x8*)(shb + (BUF)*BSZ + rdA + (MOFF)*2048 + sA1);            \
    bf16x8 a2 = *(const bf16x8*)(shb + (BUF)*BSZ + rdA + ((MOFF)+1)*2048 + sA0);        \
    bf16x8 a3 = *(const bf16x8*)(shb + (BUF)*BSZ + rdA + ((MOFF)+1)*2048 + sA1);
#define RDBALL(BUF, BB)                                                                 \
    _Pragma("unroll") for (int nn = 0; nn < NF; ++nn){                                  \
      BB[nn][0] = *(const bf16x8*)(shb + (BUF)*BSZ + rdB + nn*2048 + sA0);              \
      BB[nn][1] = *(const bf16x8*)(shb + (BUF)*BSZ + rdB + nn*2048 + sA1);              \
    }
#define MM24(MOFF, BB)                                                                  \
    _Pragma("unroll") for (int nn = 0; nn < NF; ++nn)                                   \
      acc[(MOFF)+0][nn] = __builtin_amdgcn_mfma_f32_16x16x32_bf16(a0, BB[nn][0], acc[(MOFF)+0][nn],0,0,0); \
    _Pragma("unroll") for (int nn = 0; nn < NF; ++nn)                                   \
      acc[(MOFF)+1][nn] = __builtin_amdgcn_mfma_f32_16x16x32_bf16(a2, BB[nn][0], acc[(MOFF)+1][nn],0,0,0); \
    _Pragma("unroll") for (int nn = 0; nn < NF; ++nn)                                   \
      acc[(MOFF)+0][nn] = __builtin_amdgcn_mfma_f32_16x16x32_bf16(a1, BB[nn][1], acc[(MOFF)+0][nn],0,0,0); \
    _Pragma("unroll") for (int nn = 0; nn < NF; ++nn)                                   \
      acc[(MOFF)+1][nn] = __builtin_amdgcn_mfma_f32_16x16x32_bf16(a3, BB[nn][1], acc[(MOFF)+1][nn],0,0,0);
#define ENDPH                                                                           \
    __builtin_amdgcn_s_setprio(0);                                                      \
    __builtin_amdgcn_s_barrier();                                                       \
    __builtin_amdgcn_sched_barrier(0);

template<int NF, typename OT>
__global__ __launch_bounds__(256, 2)
void k_gemmw(const u16* __restrict__ A, const u16* __restrict__ Bm,
             OT* __restrict__ C, int ldc, int K, int nkt){
  constexpr int BSZ = 16384 + NF*4096;
  __shared__ char shb[2*BSZ];
  const int tid = threadIdx.x, ln = tid & 63, wid = tid >> 6;
  const int wm = wid >> 1, wn = wid & 1;
  const int lr = ln & 15, lg = ln >> 4;

  const int gx = gridDim.x;
  const int mt = gridDim.y;
  const int lin = blockIdx.y * gx + blockIdx.x;
  const int xcd = lin & 7, sub = lin >> 3;
  const int ncx = gx >> 3;
  const int n_local = sub / mt;
  const int m_idx   = sub % mt;
  const int m0 = m_idx << 7;
  const int n0 = (xcd * ncx + n_local) * (NF*32);

  const int srow = tid >> 3;
  const int slog = ((tid & 7) ^ (srow & 7)) * 8;
  const u16* pA = A + (size_t)(m0 + srow)*K + slog;
  const u16* pB = Bm + (size_t)(n0 + srow)*K + slog;

  const int sA0 = (lg ^ (ln & 7)) << 4;
  const int sA1 = ((4 + lg) ^ (ln & 7)) << 4;
  const u32 rdA = wm*8192 + lr*128;
  const u32 rdB = 16384 + wn*(NF*2048) + lr*128;

  f32x4 acc[4][NF] = {};

  STA(0,0,0); STA(0,1,0); STA(0,2,0); STA(0,3,0);
  #pragma unroll
  for (int hh = 0; hh < NF; ++hh) STB(0, hh, 0);
  #pragma unroll
  for (int hh = 0; hh < NF; ++hh) STB(1, hh, 1);
  VMWN;
  __builtin_amdgcn_s_barrier();
  __builtin_amdgcn_sched_barrier(0);

  const int nit = nkt >> 1;
  #pragma unroll 1
  for (int it = 0; it < nit; ++it){
    const int t1 = 2*it + 1;
    int t2 = 2*it + 2; if (t2 >= nkt) t2 = 0;
    int t3 = 2*it + 3; if (t3 >= nkt) t3 = 1;
    bf16x8 bb0[NF][2], bb1[NF][2];
    { RDA4(0, 0) RDBALL(0, bb0)
      STA(1,0,t1); STA(1,1,t1); STA(1,2,t1); STA(1,3,t1);
      __builtin_amdgcn_s_setprio(1);
      MM24(0, bb0)
      ENDPH }
    { RDA4(0, 2)
      #pragma unroll
      for (int hh = 0; hh < NF; ++hh) STB(0, hh, t2);
      VMWN;
      __builtin_amdgcn_s_setprio(1);
      MM24(2, bb0)
      ENDPH }
    { RDA4(1, 0) RDBALL(1, bb1)
      STA(0,0,t2); STA(0,1,t2); STA(0,2,t2); STA(0,3,t2);
      __builtin_amdgcn_s_setprio(1);
      MM24(0, bb1)
      ENDPH }
    { RDA4(1, 2)
      #pragma unroll
      for (int hh = 0; hh < NF; ++hh) STB(1, hh, t3);
      VMWN;
      __builtin_amdgcn_s_setprio(1);
      MM24(2, bb1)
      ENDPH }
  }
  asm volatile("s_waitcnt vmcnt(0)" ::: "memory");

  const int crow = m0 + wm*64 + lg*4;
  const int ccol = n0 + wn*(NF*16) + lr;
  #pragma unroll
  for (int m = 0; m < 4; ++m)
    #pragma unroll
    for (int nn = 0; nn < NF; ++nn)
      #pragma unroll
      for (int r = 0; r < 4; ++r){
        float v = acc[m][nn][r];
        if constexpr (__is_same(OT, float))
          C[(size_t)(crow + m*16 + r)*ldc + ccol + nn*16] = v;
        else
          C[(size_t)(crow + m*16 + r)*ldc + ccol + nn*16] = f2bf(v);
      }
}

// ========== out_proj GEMM: BM=256 x BN=128, 4 waves, wave tile 128x64 (375 B/MFMA) ==========
// 256 thr (4 waves, 2Mx2N). BK=64. LDS = 2 x (A 32KB + B 16KB) = 96KB -> 1 block/CU.
// grid 32x8 = 256 blocks = exactly one round, full K (no split-K, no add pass).
// Serialized read+MFMA model: per CU/K-tile MFMA 1242 cyc + reads 750 cyc -> ~62% util.
// Ledger (A=8 issues/K-tile of 32 rows, B=4): prologue A-t0+B-t0(12)+B-t1(4); wait(4)
// => buf0 landed. P0: rd A m0-3 + B of buf0; +8 A-t1 (12); MFMA m0-3; bar.
// P1: rd A m4-7; +4 B-t2 (16); wait(4) => buf1 (8 A-t1 + 4 B-t1) landed; MFMA m4-7; bar.
// P2/P3 symmetric. Region safety: each staged region's prior reads drained by a
// preceding phase's MFMA (lgkm dep) before its barrier. Same T2 swizzle / XCD chunking.
#define OSTA(BUF,HH,KT) gld_lds16(qA + (size_t)((HH)*32)*K + (size_t)(KT)*64, shb + (BUF)*49152 + (HH)*4096 + tid*16)
#define OSTB(BUF,HH,KT) gld_lds16(qB + (size_t)((HH)*32)*K + (size_t)(KT)*64, shb + (BUF)*49152 + 32768 + (HH)*4096 + tid*16)
#define OVMW do { asm volatile("s_waitcnt vmcnt(4)" ::: "memory"); __builtin_amdgcn_sched_barrier(0); } while(0)
#define ORDA(BUF, MOFF, AA)                                                             \
    _Pragma("unroll") for (int mm = 0; mm < 4; ++mm){                                   \
      AA[mm][0] = *(const bf16x8*)(shb + (BUF)*49152 + rdA + ((MOFF)+mm)*2048 + sA0);   \
      AA[mm][1] = *(const bf16x8*)(shb + (BUF)*49152 + rdA + ((MOFF)+mm)*2048 + sA1);   \
    }
#define ORDB(BUF, BB)                                                                   \
    _Pragma("unroll") for (int nn = 0; nn < 4; ++nn){                                   \
      BB[nn][0] = *(const bf16x8*)(shb + (BUF)*49152 + rdB + nn*2048 + sA0);            \
      BB[nn][1] = *(const bf16x8*)(shb + (BUF)*49152 + rdB + nn*2048 + sA1);            \
    }
#define OMM(MOFF, AA, BB)                                                               \
    _Pragma("unroll") for (int mm = 0; mm < 4; ++mm)                                    \
      _Pragma("unroll") for (int nn = 0; nn < 4; ++nn)                                  \
        acc[(MOFF)+mm][nn] = __builtin_amdgcn_mfma_f32_16x16x32_bf16(AA[mm][0], BB[nn][0], acc[(MOFF)+mm][nn],0,0,0); \
    _Pragma("unroll") for (int mm = 0; mm < 4; ++mm)                                    \
      _Pragma("unroll") for (int nn = 0; nn < 4; ++nn)                                  \
        acc[(MOFF)+mm][nn] = __builtin_amdgcn_mfma_f32_16x16x32_bf16(AA[mm][1], BB[nn][1], acc[(MOFF)+mm][nn],0,0,0);

__global__ __launch_bounds__(256, 1)
void k_gemmo(const u16* __restrict__ A, const u16* __restrict__ Bm,
             float* __restrict__ C, int ldc, int K, int nkt){
  __shared__ char shb[98304];
  const int tid = threadIdx.x, ln = tid & 63, wid = tid >> 6;
  const int wm = wid >> 1, wn = wid & 1;
  const int lr = ln & 15, lg = ln >> 4;

  const int gx = gridDim.x;                 // 32 n-tiles (BN=128)
  const int mt = gridDim.y;                 // 8 m-tiles (BM=256)
  const int lin = blockIdx.y * gx + blockIdx.x;
  const int xcd = lin & 7, sub = lin >> 3;
  const int ncx = gx >> 3;
  const int n_local = sub / mt;
  const int m_idx   = sub % mt;
  const int m0 = m_idx << 8;                // BM = 256
  const int n0 = (xcd * ncx + n_local) << 7;// BN = 128

  const int srow = tid >> 3;
  const int slog = ((tid & 7) ^ (srow & 7)) * 8;
  const u16* qA = A + (size_t)(m0 + srow)*K + slog;
  const u16* qB = Bm + (size_t)(n0 + srow)*K + slog;

  const int sA0 = (lg ^ (ln & 7)) << 4;
  const int sA1 = ((4 + lg) ^ (ln & 7)) << 4;
  const u32 rdA = wm*16384 + lr*128;        // wave m-half = 128 rows
  const u32 rdB = 32768 + wn*8192 + lr*128; // wave n-half = 64 cols

  f32x4 acc[8][4] = {};

  // prologue
  #pragma unroll
  for (int hh = 0; hh < 8; ++hh) OSTA(0, hh, 0);
  #pragma unroll
  for (int hh = 0; hh < 4; ++hh) OSTB(0, hh, 0);
  #pragma unroll
  for (int hh = 0; hh < 4; ++hh) OSTB(1, hh, 1);
  OVMW;
  __builtin_amdgcn_s_barrier();
  __builtin_amdgcn_sched_barrier(0);

  const int nit = nkt >> 1;
  #pragma unroll 1
  for (int it = 0; it < nit; ++it){
    const int t1 = 2*it + 1;
    int t2 = 2*it + 2; if (t2 >= nkt) t2 = 0;
    int t3 = 2*it + 3; if (t3 >= nkt) t3 = 1;
    bf16x8 aa[4][2], bb0[4][2], bb1[4][2];
    { // P0
      ORDA(0, 0, aa) ORDB(0, bb0)
      #pragma unroll
      for (int hh = 0; hh < 8; ++hh) OSTA(1, hh, t1);
      __builtin_amdgcn_s_setprio(1);
      OMM(0, aa, bb0)
      ENDPH }
    { // P1
      ORDA(0, 4, aa)
      #pragma unroll
      for (int hh = 0; hh < 4; ++hh) OSTB(0, hh, t2);
      OVMW;
      __builtin_amdgcn_s_setprio(1);
      OMM(4, aa, bb0)
      ENDPH }
    { // P2
      ORDA(1, 0, aa) ORDB(1, bb1)
      #pragma unroll
      for (int hh = 0; hh < 8; ++hh) OSTA(0, hh, t2);
      __builtin_amdgcn_s_setprio(1);
      OMM(0, aa, bb1)
      ENDPH }
    { // P3
      ORDA(1, 4, aa)
      #pragma unroll
      for (int hh = 0; hh < 4; ++hh) OSTB(1, hh, t3);
      OVMW;
      __builtin_amdgcn_s_setprio(1);
      OMM(4, aa, bb1)
      ENDPH }
  }
  asm volatile("s_waitcnt vmcnt(0)" ::: "memory");

  const int crow = m0 + wm*128 + lg*4;
  const int ccol = n0 + wn*64 + lr;
  #pragma unroll
  for (int m = 0; m < 8; ++m)
    #pragma unroll
    for (int nn = 0; nn < 4; ++nn)
      #pragma unroll
      for (int r = 0; r < 4; ++r)
        C[(size_t)(crow + m*16 + r)*ldc + ccol + nn*16] = acc[m][nn][r];
}

// ---------------- conv1d(K=4) + SiLU + split (8ch/thread, u16x8 I/O) ----------------
__global__ __launch_bounds__(256)
void k_conv(const u16* __restrict__ proj16, const float* __restrict__ cw,
            const float* __restrict__ cb, u16* __restrict__ x16,
            u16* __restrict__ B16, u16* __restrict__ C16){
  const int ch0 = blockIdx.x*2048 + threadIdx.x*8;
  const int tbase = blockIdx.y*16;
  f32x4 w[8]; float bias[8];
  #pragma unroll
  for (int j = 0; j < 8; ++j){
    w[j] = *(const f32x4*)&cw[(size_t)(ch0+j)*4];
    bias[j] = cb[ch0+j];
  }
  const u16* pcol = proj16 + INTER_N + ch0;
  float p0[8], p1[8], p2[8];
  if (tbase >= 3){
    u16x8 v0 = *(const u16x8*)&pcol[(size_t)(tbase-3)*PROJ_N];
    u16x8 v1 = *(const u16x8*)&pcol[(size_t)(tbase-2)*PROJ_N];
    u16x8 v2 = *(const u16x8*)&pcol[(size_t)(tbase-1)*PROJ_N];
    #pragma unroll
    for (int j = 0; j < 8; ++j){ p0[j]=bf2f(v0[j]); p1[j]=bf2f(v1[j]); p2[j]=bf2f(v2[j]); }
  } else {
    #pragma unroll
    for (int j = 0; j < 8; ++j){ p0[j]=0.f; p1[j]=0.f; p2[j]=0.f; }
  }
  u16* xdst = (ch0 < INTER_N) ? x16 + ch0
            : (ch0 < INTER_N + 1024) ? B16 + (ch0 - INTER_N)
            : C16 + (ch0 - INTER_N - 1024);
  const int dstride = (ch0 < INTER_N) ? INTER_N : 1024;
  #pragma unroll 2
  for (int i = 0; i < 16; ++i){
    int t = tbase + i;
    u16x8 cv = *(const u16x8*)&pcol[(size_t)t*PROJ_N];
    u16x8 o;
    #pragma unroll
    for (int j = 0; j < 8; ++j){
      float cur = bf2f(cv[j]);
      float a = bias[j] + w[j][0]*p0[j] + w[j][1]*p1[j] + w[j][2]*p2[j] + w[j][3]*cur;
      o[j] = f2bf(a / (1.f + __expf(-a)));
      p0[j] = p1[j]; p1[j] = p2[j]; p2[j] = cur;
    }
    *(u16x8*)&xdst[(size_t)t*dstride] = o;
  }
}

// ---------------- SSD part A ----------------
__global__ __launch_bounds__(512)
void k_ssda(const u16* __restrict__ B16, const u16* __restrict__ x16,
            const float* __restrict__ dtv, const float* __restrict__ cum,
            const float* __restrict__ cumend, u16* __restrict__ SlocT){
  __shared__ u16 lBdT[128*136];
  __shared__ u16 lXdT[64*136];
  __shared__ float lDec[128], lDt[128];
  const int tid = threadIdx.x, wid = tid >> 6, ln = tid & 63;
  const int c = blockIdx.x >> 7, h = blockIdx.x & 127, g = h >> 4;
  if (tid < 128){
    int t = c*128 + tid;
    lDec[tid] = __expf(cumend[c*128 + h] - cum[(size_t)t*128 + h]);
    lDt[tid]  = dtv[(size_t)t*128 + h];
  }
  __syncthreads();
  for (int it = 0; it < 32; ++it){
    int idx = it*512 + tid;
    int q = idx >> 7, n = idx & 127;
    float bv = bf2f(B16[(size_t)(c*128 + q)*1024 + g*128 + n]) * lDec[q];
    lBdT[n*136 + q] = f2bf(bv);
  }
  for (int it = 0; it < 16; ++it){
    int idx = it*512 + tid;
    int q = idx >> 6, p = idx & 63;
    float xv = bf2f(x16[(size_t)(c*128 + q)*INTER_N + h*64 + p]) * lDt[q];
    lXdT[p*136 + q] = f2bf(xv);
  }
  __syncthreads();
  const int wr = wid >> 1, wc = wid & 1;
  const int kofs = (ln >> 4) << 3;
  f32x4 acc[2][2] = {};
  #pragma unroll
  for (int ks = 0; ks < 4; ++ks){
    bf16x8 a[2], b[2];
    #pragma unroll
    for (int m = 0; m < 2; ++m) a[m] = *(const bf16x8*)&lBdT[(wr*32 + m*16 + (ln & 15))*136 + ks*32 + kofs];
    #pragma unroll
    for (int n = 0; n < 2; ++n) b[n] = *(const bf16x8*)&lXdT[(wc*32 + n*16 + (ln & 15))*136 + ks*32 + kofs];
    #pragma unroll
    for (int m = 0; m < 2; ++m)
      #pragma unroll
      for (int n = 0; n < 2; ++n)
        acc[m][n] = __builtin_amdgcn_mfma_f32_16x16x32_bf16(a[m], b[n], acc[m][n], 0, 0, 0);
  }
  const size_t base = (size_t)(c*128 + h) * 8192;
  #pragma unroll
  for (int m = 0; m < 2; ++m)
    #pragma unroll
    for (int n = 0; n < 2; ++n){
      int p  = wc*32 + n*16 + (ln & 15);
      int nn = wr*32 + m*16 + ((ln >> 4) << 2);
      u16x4 o = { f2bf(acc[m][n][0]), f2bf(acc[m][n][1]), f2bf(acc[m][n][2]), f2bf(acc[m][n][3]) };
      *(u16x4*)&SlocT[base + (size_t)p*128 + nn] = o;
    }
}

// ---------------- chunk scan (u16x8) ----------------
__global__ __launch_bounds__(256)
void k_scan(const u16* __restrict__ SlocT, const float* __restrict__ dec,
            u16* __restrict__ SprevT){
  int idx = blockIdx.x*256 + threadIdx.x;
  int h = idx >> 10, p = (idx >> 4) & 63, n8 = (idx & 15)*8;
  float s[8] = {};
  for (int c = 0; c < NC_N; ++c){
    size_t off = (size_t)(c*128 + h)*8192 + (size_t)p*128 + n8;
    u16x8 o;
    #pragma unroll
    for (int j = 0; j < 8; ++j) o[j] = f2bf(s[j]);
    *(u16x8*)&SprevT[off] = o;
    u16x8 sl = *(const u16x8*)&SlocT[off];
    float d = dec[c*128 + h];
    #pragma unroll
    for (int j = 0; j < 8; ++j) s[j] = d*s[j] + bf2f(sl[j]);
  }
}

// ---------------- SSD part B ----------------
__global__ __launch_bounds__(512)
void k_ssdb(const u16* __restrict__ C16, const u16* __restrict__ B16g,
            const u16* __restrict__ x16, const float* __restrict__ dtv,
            const float* __restrict__ cum, const u16* __restrict__ SprevT,
            const u16* __restrict__ proj16, const float* __restrict__ Dres,
            u16* __restrict__ yg16){
  __shared__ u16 lC[128*136];
  __shared__ u16 lBP[128*136];
  __shared__ u16 lXdT[64*136];
  __shared__ float lCum[128], lDt[128];
  const int tid = threadIdx.x, wid = tid >> 6, ln = tid & 63;
  const int c = blockIdx.x >> 7, h = blockIdx.x & 127, g = h >> 4;
  if (tid < 128){
    int t = c*128 + tid;
    lCum[tid] = cum[(size_t)t*128 + h];
    lDt[tid]  = dtv[(size_t)t*128 + h];
  }
  __syncthreads();
  #pragma unroll
  for (int it = 0; it < 4; ++it){
    int idx = it*512 + tid;
    int q = idx >> 4, n8 = (idx & 15) << 3;
    size_t gi = (size_t)(c*128 + q)*1024 + g*128 + n8;
    *(u16x8*)&lC[q*136 + n8]  = *(const u16x8*)&C16[gi];
    *(u16x8*)&lBP[q*136 + n8] = *(const u16x8*)&B16g[gi];
  }
  for (int it = 0; it < 16; ++it){
    int idx = it*512 + tid;
    int q = idx >> 6, p = idx & 63;
    lXdT[p*136 + q] = f2bf(bf2f(x16[(size_t)(c*128 + q)*INTER_N + h*64 + p]) * lDt[q]);
  }
  __syncthreads();
  const int kofs = (ln >> 4) << 3;
  {
    const int wr = wid >> 2, wc = wid & 3;
    f32x4 cb[4][2] = {};
    #pragma unroll
    for (int ks = 0; ks < 4; ++ks){
      bf16x8 a[4], b[2];
      #pragma unroll
      for (int m = 0; m < 4; ++m) a[m] = *(const bf16x8*)&lC[(wr*64 + m*16 + (ln & 15))*136 + ks*32 + kofs];
      #pragma unroll
      for (int n = 0; n < 2; ++n) b[n] = *(const bf16x8*)&lBP[(wc*32 + n*16 + (ln & 15))*136 + ks*32 + kofs];
      #pragma unroll
      for (int m = 0; m < 4; ++m)
        #pragma unroll
        for (int n = 0; n < 2; ++n)
          cb[m][n] = __builtin_amdgcn_mfma_f32_16x16x32_bf16(a[m], b[n], cb[m][n], 0, 0, 0);
    }
    __syncthreads();
    #pragma unroll
    for (int m = 0; m < 4; ++m)
      #pragma unroll
      for (int n = 0; n < 2; ++n){
        int kcol = (wid & 3)*32 + n*16 + (ln & 15);
        float ck = lCum[kcol];
        #pragma unroll
        for (int r = 0; r < 4; ++r){
          int q = (wid >> 2)*64 + m*16 + ((ln >> 4) << 2) + r;
          float v = (kcol <= q) ? cb[m][n][r] * __expf(lCum[q] - ck) : 0.f;
          lBP[q*136 + kcol] = f2bf(v);
        }
      }
  }
  __syncthreads();
  const int yr = wid >> 1, yc = wid & 1;
  f32x4 y1[2][2] = {}, y2[2][2] = {};
  const size_t spbase = (size_t)(c*128 + h) * 8192;
  #pragma unroll
  for (int ks = 0; ks < 4; ++ks){
    bf16x8 ap[2], acf[2], bx[2], bs[2];
    #pragma unroll
    for (int m = 0; m < 2; ++m){
      int qr = yr*32 + m*16 + (ln & 15);
      ap[m]  = *(const bf16x8*)&lBP[qr*136 + ks*32 + kofs];
      acf[m] = *(const bf16x8*)&lC [qr*136 + ks*32 + kofs];
    }
    #pragma unroll
    for (int n = 0; n < 2; ++n){
      int p = yc*32 + n*16 + (ln & 15);
      bx[n] = *(const bf16x8*)&lXdT[p*136 + ks*32 + kofs];
      bs[n] = *(const bf16x8*)&SprevT[spbase + (size_t)p*128 + ks*32 + kofs];
    }
    #pragma unroll
    for (int m = 0; m < 2; ++m)
      #pragma unroll
      for (int n = 0; n < 2; ++n){
        y1[m][n] = __builtin_amdgcn_mfma_f32_16x16x32_bf16(ap[m],  bx[n], y1[m][n], 0, 0, 0);
        y2[m][n] = __builtin_amdgcn_mfma_f32_16x16x32_bf16(acf[m], bs[n], y2[m][n], 0, 0, 0);
      }
  }
  const float dh = Dres[h];
  #pragma unroll
  for (int m = 0; m < 2; ++m)
    #pragma unroll
    for (int r = 0; r < 4; ++r){
      int q = yr*32 + m*16 + ((ln >> 4) << 2) + r;
      float eq = __expf(lCum[q]);
      size_t t = (size_t)(c*128 + q);
      #pragma unroll
      for (int n = 0; n < 2; ++n){
        int p = yc*32 + n*16 + (ln & 15);
        int chn = h*64 + p;
        float xv = bf2f(x16[t*INTER_N + chn]);
        float zv = bf2f(proj16[t*PROJ_N + chn]);
        float yv = y1[m][n][r] + eq*y2[m][n][r] + dh*xv;
        float sg = zv / (1.f + __expf(-zv));
        yg16[t*INTER_N + chn] = f2bf(yv * sg);
      }
    }
}

// ---------------- gated RMSNorm over INTER (bf16 in, bf16 out) ----------------
__global__ __launch_bounds__(256)
void k_gnorm(const u16* __restrict__ yg, const float* __restrict__ gnw,
             u16* __restrict__ yn16){
  __shared__ float red[4];
  const int row = blockIdx.x, tid = threadIdx.x;
  const u16* rp = yg + (size_t)row * INTER_N;
  u16x8 v[4];
  float ss = 0.f;
  #pragma unroll
  for (int i = 0; i < 4; ++i){
    v[i] = *(const u16x8*)&rp[(size_t)(tid + i*256)*8];
    #pragma unroll
    for (int j = 0; j < 8; ++j){ float f = bf2f(v[i][j]); ss += f*f; }
  }
  #pragma unroll
  for (int o = 32; o > 0; o >>= 1) ss += __shfl_down(ss, o, 64);
  if ((tid & 63) == 0) red[tid >> 6] = ss;
  __syncthreads();
  float tot = (red[0] + red[1]) + (red[2] + red[3]);
  float sc = rsqrtf(tot / (float)INTER_N + 1e-5f);
  #pragma unroll
  for (int i = 0; i < 4; ++i){
    int c8 = (tid + i*256)*8;
    u16x8 o;
    #pragma unroll
    for (int j = 0; j < 8; ++j)
      o[j] = f2bf(bf2f(v[i][j]) * sc * gnw[c8 + j]);
    *(u16x8*)&yn16[(size_t)row*INTER_N + c8] = o;
  }
}

// =====================================================================================
extern "C" void kernel_launch(void* const* d_in, const int* in_sizes, int n_in,
                              void* d_out, int out_size, void* d_ws, size_t ws_size,
                              hipStream_t stream){
  (void)in_sizes; (void)n_in; (void)out_size;
  const float* hs_in     = (const float*)d_in[0];
  const float* res_in    = (const float*)d_in[1];
  const float* norm_w    = (const float*)d_in[2];
  const float* in_proj_w = (const float*)d_in[3];
  const float* conv_w    = (const float*)d_in[4];
  const float* conv_b    = (const float*)d_in[5];
  const float* A_log     = (const float*)d_in[6];
  const float* D_res     = (const float*)d_in[7];
  const float* dt_bias   = (const float*)d_in[8];
  const float* gn_w      = (const float*)d_in[9];
  const float* out_proj_w= (const float*)d_in[10];

  float* out0      = (float*)d_out;
  float* resid_out = out0 + (size_t)T_N * D_N;

  char* ws = (char*)d_ws;
  const size_t o_hs16   = 0;
  const size_t o_Win16  = 16777216;
  const size_t o_Wout16 = 168820736;
  const size_t o_proj   = 235929600;
  const size_t o_Wn     = 387973120;
  const size_t o_dtv    = 391118848;
  const size_t o_cum    = 392167424;
  const size_t o_cumend = 393216000;
  const size_t o_dec    = 393224192;
  const size_t o_rstd   = 393232384;
  const size_t o_x16    = 393240576;
  const size_t o_B16    = 426795008;
  const size_t o_C16    = 430989312;
  const size_t o_SlocT  = 435183616;
  const size_t o_SprevT = 468738048;
  const size_t o_yn16   = 502292480;
  const size_t WS_NEED  = 535846912;
  if (ws_size < WS_NEED) return;

  u16*   hs16   = (u16*)  (ws + o_hs16);
  u16*   Win16  = (u16*)  (ws + o_Win16);
  u16*   Wout16 = (u16*)  (ws + o_Wout16);
  u16*   proj16 = (u16*)  (ws + o_proj);
  float* Wn     = (float*)(ws + o_Wn);
  float* dtpart = (float*)(ws + o_proj);
  float* dta    = (float*)(ws + o_proj + (16u<<20));
  float* dtv    = (float*)(ws + o_dtv);
  float* cum    = (float*)(ws + o_cum);
  float* cumend = (float*)(ws + o_cumend);
  float* dec    = (float*)(ws + o_dec);
  float* rstd   = (float*)(ws + o_rstd);
  u16*   x16    = (u16*)  (ws + o_x16);
  u16*   B16    = (u16*)  (ws + o_B16);
  u16*   C16    = (u16*)  (ws + o_C16);
  u16*   SlocT  = (u16*)  (ws + o_SlocT);
  u16*   SprevT = (u16*)  (ws + o_SprevT);
  u16*   yn16   = (u16*)  (ws + o_yn16);
  u16*   yg16   = (u16*)  (ws + o_Win16);

  k_addnorm<<<T_N, 256, 0, stream>>>(hs_in, res_in, norm_w, resid_out, hs16, rstd);
  k_cvt2<<<6144, 256, 0, stream>>>(in_proj_w, Win16, (size_t)NGEMM_N * D_N / 4,
                                   out_proj_w, Wout16, (size_t)D_N * INTER_N / 4);
  k_wdt<<<128, 256, 0, stream>>>(in_proj_w, norm_w, Wn);
  k_dtgemm<<<1024, 256, 0, stream>>>(resid_out, Wn, dtpart);
  k_dtsum<<<1024, 256, 0, stream>>>(dtpart, rstd, dt_bias, A_log, dtv, dta);
  k_dtprep<<<NC_N, 128, 0, stream>>>(dta, cum, cumend, dec);
  // in_proj: BM=128, BN=192 (NF=6): grid 96 x 16 = 1536 = 3 exact rounds at 2 blocks/CU
  k_gemmw<6, u16><<<dim3(NGEMM_N/192, T_N/128), 256, 0, stream>>>(hs16, Win16, proj16, PROJ_N, D_N, D_N/64);
  k_conv<<<dim3(CONVD_N/2048, T_N/16), 256, 0, stream>>>(proj16, conv_w, conv_b, x16, B16, C16);
  k_ssda<<<NC_N * H_N, 512, 0, stream>>>(B16, x16, dtv, cum, cumend, SlocT);
  k_scan<<<512, 256, 0, stream>>>(SlocT, dec, SprevT);
  k_ssdb<<<NC_N * H_N, 512, 0, stream>>>(C16, B16, x16, dtv, cum, SprevT, proj16, D_res, yg16);
  k_gnorm<<<T_N, 256, 0, stream>>>(yg16, gn_w, yn16);
  // out_proj: BM=256, BN=128: grid 32 x 8 = 256 blocks = exactly one round at 1 block/CU
  k_gemmo<<<dim3(D_N/128, T_N/256), 256, 0, stream>>>(yn16, Wout16, out0, D_N, INTER_N, INTER_N/64);
}

// Round 15
// 821.478 us; speedup vs baseline: 1.0034x; 1.0034x over previous
//
#include <hip/hip_runtime.h>
#include <stdint.h>

typedef unsigned short u16;
typedef unsigned int   u32;
typedef float  f32x4  __attribute__((ext_vector_type(4)));
typedef __bf16 bf16x8 __attribute__((ext_vector_type(8)));
typedef u16    u16x4  __attribute__((ext_vector_type(4)));
typedef u16    u16x8  __attribute__((ext_vector_type(8)));

#define T_N     2048
#define D_N     4096
#define H_N     128
#define P_N     64
#define G_N     8
#define NS_N    128
#define INTER_N 8192
#define CONVD_N 10240
#define PROJ_N  18560
#define NGEMM_N 18432
#define NC_N    16

__device__ __forceinline__ float bf2f(u16 u){ u32 x = ((u32)u) << 16; return __builtin_bit_cast(float, x); }
__device__ __forceinline__ u16 f2bf(float f){
  u32 u = __builtin_bit_cast(u32, f);
  u += 0x7FFFu + ((u >> 16) & 1u);
  return (u16)(u >> 16);
}

__device__ __forceinline__ void gld_lds16(const void* g, void* lds){
  __builtin_amdgcn_global_load_lds(
      (const __attribute__((address_space(1))) void*)(uintptr_t)g,
      (__attribute__((address_space(3))) void*)(u32)(uintptr_t)lds,
      16, 0, 0);
}

// ---------------- add + RMSNorm ----------------
__global__ __launch_bounds__(256)
void k_addnorm(const float* __restrict__ hin, const float* __restrict__ rin,
               const float* __restrict__ nw, float* __restrict__ resid,
               u16* __restrict__ hs16, float* __restrict__ rstd){
  __shared__ float red[4];
  const int row = blockIdx.x, tid = threadIdx.x;
  const size_t rb = (size_t)row * D_N;
  f32x4 s[4];
  float ss = 0.f;
  #pragma unroll
  for (int i = 0; i < 4; ++i){
    int c4 = tid + i*256;
    f32x4 a = *(const f32x4*)&hin[rb + (size_t)c4*4];
    f32x4 b = *(const f32x4*)&rin[rb + (size_t)c4*4];
    s[i] = a + b;
    *(f32x4*)&resid[rb + (size_t)c4*4] = s[i];
    ss += s[i][0]*s[i][0] + s[i][1]*s[i][1] + s[i][2]*s[i][2] + s[i][3]*s[i][3];
  }
  #pragma unroll
  for (int o = 32; o > 0; o >>= 1) ss += __shfl_down(ss, o, 64);
  if ((tid & 63) == 0) red[tid >> 6] = ss;
  __syncthreads();
  float tot = (red[0] + red[1]) + (red[2] + red[3]);
  float rs = rsqrtf(tot / (float)D_N + 1e-5f);
  if (tid == 0) rstd[row] = rs;
  #pragma unroll
  for (int i = 0; i < 4; ++i){
    int c4 = tid + i*256;
    f32x4 w = *(const f32x4*)&nw[(size_t)c4*4];
    u16x4 o = { f2bf(s[i][0]*rs*w[0]), f2bf(s[i][1]*rs*w[1]),
                f2bf(s[i][2]*rs*w[2]), f2bf(s[i][3]*rs*w[3]) };
    *(u16x4*)&hs16[rb + (size_t)c4*4] = o;
  }
}

// ---------------- fp32 -> bf16 conversion (both weights in one launch) ----------------
__global__ void k_cvt2(const float* __restrict__ in1, u16* __restrict__ out1, size_t n4a,
                       const float* __restrict__ in2, u16* __restrict__ out2, size_t n4b){
  size_t i = (size_t)blockIdx.x * blockDim.x + threadIdx.x;
  size_t stride = (size_t)gridDim.x * blockDim.x;
  size_t tot = n4a + n4b;
  for (; i < tot; i += stride){
    const float* in = (i < n4a) ? in1 : in2;
    u16* out = (i < n4a) ? out1 : out2;
    size_t j = (i < n4a) ? i : i - n4a;
    f32x4 v = *(const f32x4*)&in[j*4];
    u16x4 o = { f2bf(v[0]), f2bf(v[1]), f2bf(v[2]), f2bf(v[3]) };
    *(u16x4*)&out[j*4] = o;
  }
}

// ---------------- Wn[d][h] = in_proj_w[18432+h][d] * norm_w[d]  (LDS transpose) ----------
__global__ __launch_bounds__(256)
void k_wdt(const float* __restrict__ W, const float* __restrict__ nw,
           float* __restrict__ Wn){
  __shared__ float lt[32][133];
  const int tid = threadIdx.x;
  const int d0 = blockIdx.x * 32;
  #pragma unroll
  for (int i = 0; i < 16; ++i){
    int h = i*8 + (tid >> 5);
    int d = tid & 31;
    lt[d][h] = W[(size_t)(INTER_N + CONVD_N + h)*D_N + d0 + d];
  }
  __syncthreads();
  #pragma unroll
  for (int i = 0; i < 4; ++i){
    int d = i*8 + (tid >> 5);
    int h4 = (tid & 31) * 4;
    float nwv = nw[d0 + d];
    f32x4 v = { lt[d][h4]*nwv, lt[d][h4+1]*nwv, lt[d][h4+2]*nwv, lt[d][h4+3]*nwv };
    *(f32x4*)&Wn[(size_t)(d0 + d)*128 + h4] = v;
  }
}

// ---------------- fp32 dt GEMM, split-K x8 (f32x4 LDS reads) ----------------
__global__ __launch_bounds__(256)
void k_dtgemm(const float* __restrict__ resid, const float* __restrict__ Wn,
              float* __restrict__ dtpart){
  __shared__ float lhs[16*128];
  const int tid = threadIdx.x;
  const int tb = blockIdx.x >> 3, ks = blockIdx.x & 7;
  const int t0 = tb * 16;
  const int k0 = ks * (D_N / 8);
  const int hcol = tid & 127, rh = tid >> 7;
  float acc[8] = {0,0,0,0,0,0,0,0};
  for (int kt = k0; kt < k0 + D_N/8; kt += 128){
    __syncthreads();
    #pragma unroll
    for (int it = 0; it < 2; ++it){
      int idx = it*256 + tid;
      int rr = idx >> 5, c4 = idx & 31;
      *(f32x4*)&lhs[rr*128 + c4*4] = *(const f32x4*)&resid[(size_t)(t0+rr)*D_N + kt + c4*4];
    }
    __syncthreads();
    #pragma unroll 4
    for (int kk4 = 0; kk4 < 32; ++kk4){
      f32x4 w4;
      #pragma unroll
      for (int j = 0; j < 4; ++j) w4[j] = Wn[(size_t)(kt + kk4*4 + j)*128 + hcol];
      #pragma unroll
      for (int j = 0; j < 8; ++j){
        f32x4 lv = *(const f32x4*)&lhs[(rh*8 + j)*128 + kk4*4];
        acc[j] += lv[0]*w4[0] + lv[1]*w4[1] + lv[2]*w4[2] + lv[3]*w4[3];
      }
    }
  }
  #pragma unroll
  for (int j = 0; j < 8; ++j){
    int t = t0 + rh*8 + j;
    dtpart[((size_t)ks*T_N + t)*128 + hcol] = acc[j];
  }
}

// ---------------- dt sum+softplus (fully parallel) ----------------
__global__ __launch_bounds__(256)
void k_dtsum(const float* __restrict__ dtpart, const float* __restrict__ rstd,
             const float* __restrict__ dt_bias, const float* __restrict__ A_log,
             float* __restrict__ dtv, float* __restrict__ dta){
  int idx = blockIdx.x*256 + threadIdx.x;       // T*128
  int t = idx >> 7, h = idx & 127;
  float s = 0.f;
  #pragma unroll
  for (int k = 0; k < 8; ++k) s += dtpart[((size_t)k*T_N + t)*128 + h];
  float x = s * rstd[t] + dt_bias[h];
  float dv = (x > 20.f) ? x : log1pf(expf(x));
  dtv[idx] = dv;
  dta[idx] = dv * (-expf(A_log[h]));
}

// ---------------- dt cumsum per chunk ------------------------
__global__ void k_dtprep(const float* __restrict__ dta, float* __restrict__ cum,
                         float* __restrict__ cumend, float* __restrict__ dec){
  int c = blockIdx.x, h = threadIdx.x;
  float cm = 0.f;
  for (int q = 0; q < 128; ++q){
    size_t i = (size_t)(c*128 + q)*128 + h;
    cm += dta[i];
    cum[i] = cm;
  }
  cumend[c*128 + h] = cm;
  dec[c*128 + h] = expf(cm);
}

// ========== 128 x (NF*32) merged-4-phase bf16 GEMM, wave tile 64 x (NF*16) ==========
// (in_proj; unchanged — characterized at ~54% MfmaUtil, LDS-read/MFMA serialization bound)
#define STA(BUF,HH,KT) gld_lds16(pA + (size_t)((HH)*32)*K + (size_t)(KT)*64, shb + (BUF)*BSZ + (HH)*4096 + tid*16)
#define STB(BUF,HH,KT) gld_lds16(pB + (size_t)((HH)*32)*K + (size_t)(KT)*64, shb + (BUF)*BSZ + 16384 + (HH)*4096 + tid*16)
#define VMWN do { asm volatile("s_waitcnt vmcnt(%0)" :: "n"(NF) : "memory"); __builtin_amdgcn_sched_barrier(0); } while(0)
#define RDA4(BUF, MOFF)                                                                 \
    bf16x8 a0 = *(const bf16x8*)(shb + (BUF)*BSZ + rdA + (MOFF)*2048 + sA0);            \
    bf16x8 a1 = *(const bf16x8*)(shb + (BUF)*BSZ + rdA + (MOFF)*2048 + sA1);            \
    bf16x8 a2 = *(const bf16x8*)(shb + (BUF)*BSZ + rdA + ((MOFF)+1)*2048 + sA0);        \
    bf16x8 a3 = *(const bf16x8*)(shb + (BUF)*BSZ + rdA + ((MOFF)+1)*2048 + sA1);
#define RDBALL(BUF, BB)                                                                 \
    _Pragma("unroll") for (int nn = 0; nn < NF; ++nn){                                  \
      BB[nn][0] = *(const bf16x8*)(shb + (BUF)*BSZ + rdB + nn*2048 + sA0);              \
      BB[nn][1] = *(const bf16x8*)(shb + (BUF)*BSZ + rdB + nn*2048 + sA1);              \
    }
#define MM24(MOFF, BB)                                                                  \
    _Pragma("unroll") for (int nn = 0; nn < NF; ++nn)                                   \
      acc[(MOFF)+0][nn] = __builtin_amdgcn_mfma_f32_16x16x32_bf16(a0, BB[nn][0], acc[(MOFF)+0][nn],0,0,0); \
    _Pragma("unroll") for (int nn = 0; nn < NF; ++nn)                                   \
      acc[(MOFF)+1][nn] = __builtin_amdgcn_mfma_f32_16x16x32_bf16(a2, BB[nn][0], acc[(MOFF)+1][nn],0,0,0); \
    _Pragma("unroll") for (int nn = 0; nn < NF; ++nn)                                   \
      acc[(MOFF)+0][nn] = __builtin_amdgcn_mfma_f32_16x16x32_bf16(a1, BB[nn][1], acc[(MOFF)+0][nn],0,0,0); \
    _Pragma("unroll") for (int nn = 0; nn < NF; ++nn)                                   \
      acc[(MOFF)+1][nn] = __builtin_amdgcn_mfma_f32_16x16x32_bf16(a3, BB[nn][1], acc[(MOFF)+1][nn],0,0,0);
#define ENDPH                                                                           \
    __builtin_amdgcn_s_setprio(0);                                                      \
    __builtin_amdgcn_s_barrier();                                                       \
    __builtin_amdgcn_sched_barrier(0);

template<int NF, typename OT>
__global__ __launch_bounds__(256, 2)
void k_gemmw(const u16* __restrict__ A, const u16* __restrict__ Bm,
             OT* __restrict__ C, int ldc, int K, int nkt){
  constexpr int BSZ = 16384 + NF*4096;
  __shared__ char shb[2*BSZ];
  const int tid = threadIdx.x, ln = tid & 63, wid = tid >> 6;
  const int wm = wid >> 1, wn = wid & 1;
  const int lr = ln & 15, lg = ln >> 4;

  const int gx = gridDim.x;
  const int mt = gridDim.y;
  const int lin = blockIdx.y * gx + blockIdx.x;
  const int xcd = lin & 7, sub = lin >> 3;
  const int ncx = gx >> 3;
  const int n_local = sub / mt;
  const int m_idx   = sub % mt;
  const int m0 = m_idx << 7;
  const int n0 = (xcd * ncx + n_local) * (NF*32);

  const int srow = tid >> 3;
  const int slog = ((tid & 7) ^ (srow & 7)) * 8;
  const u16* pA = A + (size_t)(m0 + srow)*K + slog;
  const u16* pB = Bm + (size_t)(n0 + srow)*K + slog;

  const int sA0 = (lg ^ (ln & 7)) << 4;
  const int sA1 = ((4 + lg) ^ (ln & 7)) << 4;
  const u32 rdA = wm*8192 + lr*128;
  const u32 rdB = 16384 + wn*(NF*2048) + lr*128;

  f32x4 acc[4][NF] = {};

  STA(0,0,0); STA(0,1,0); STA(0,2,0); STA(0,3,0);
  #pragma unroll
  for (int hh = 0; hh < NF; ++hh) STB(0, hh, 0);
  #pragma unroll
  for (int hh = 0; hh < NF; ++hh) STB(1, hh, 1);
  VMWN;
  __builtin_amdgcn_s_barrier();
  __builtin_amdgcn_sched_barrier(0);

  const int nit = nkt >> 1;
  #pragma unroll 1
  for (int it = 0; it < nit; ++it){
    const int t1 = 2*it + 1;
    int t2 = 2*it + 2; if (t2 >= nkt) t2 = 0;
    int t3 = 2*it + 3; if (t3 >= nkt) t3 = 1;
    bf16x8 bb0[NF][2], bb1[NF][2];
    { RDA4(0, 0) RDBALL(0, bb0)
      STA(1,0,t1); STA(1,1,t1); STA(1,2,t1); STA(1,3,t1);
      __builtin_amdgcn_s_setprio(1);
      MM24(0, bb0)
      ENDPH }
    { RDA4(0, 2)
      #pragma unroll
      for (int hh = 0; hh < NF; ++hh) STB(0, hh, t2);
      VMWN;
      __builtin_amdgcn_s_setprio(1);
      MM24(2, bb0)
      ENDPH }
    { RDA4(1, 0) RDBALL(1, bb1)
      STA(0,0,t2); STA(0,1,t2); STA(0,2,t2); STA(0,3,t2);
      __builtin_amdgcn_s_setprio(1);
      MM24(0, bb1)
      ENDPH }
    { RDA4(1, 2)
      #pragma unroll
      for (int hh = 0; hh < NF; ++hh) STB(1, hh, t3);
      VMWN;
      __builtin_amdgcn_s_setprio(1);
      MM24(2, bb1)
      ENDPH }
  }
  asm volatile("s_waitcnt vmcnt(0)" ::: "memory");

  const int crow = m0 + wm*64 + lg*4;
  const int ccol = n0 + wn*(NF*16) + lr;
  #pragma unroll
  for (int m = 0; m < 4; ++m)
    #pragma unroll
    for (int nn = 0; nn < NF; ++nn)
      #pragma unroll
      for (int r = 0; r < 4; ++r){
        float v = acc[m][nn][r];
        if constexpr (__is_same(OT, float))
          C[(size_t)(crow + m*16 + r)*ldc + ccol + nn*16] = v;
        else
          C[(size_t)(crow + m*16 + r)*ldc + ccol + nn*16] = f2bf(v);
      }
}

// ========== out_proj GEMM: BM=256 x BN=128, 4 waves, wave tile 128x64 (375 B/MFMA) ==========
// 256 thr (4 waves, 2Mx2N). BK=64. LDS = 2 x (A 32KB + B 16KB) = 96KB -> 1 block/CU.
// grid 32x8 = 256 blocks = exactly one round, full K (no split-K, no add pass).
// Serialized read+MFMA model: per CU/K-tile MFMA 1242 cyc + reads 750 cyc -> ~62% util.
// Ledger (A=8 issues/K-tile of 32 rows, B=4): prologue A-t0+B-t0(12)+B-t1(4); wait(4)
// => buf0 landed. P0: rd A m0-3 + B of buf0; +8 A-t1 (12); MFMA m0-3; bar.
// P1: rd A m4-7; +4 B-t2 (16); wait(4) => buf1 (8 A-t1 + 4 B-t1) landed; MFMA m4-7; bar.
// P2/P3 symmetric. Region safety: each staged region's prior reads drained by a
// preceding phase's MFMA (lgkm dep) before its barrier. Same T2 swizzle / XCD chunking.
#define OSTA(BUF,HH,KT) gld_lds16(qA + (size_t)((HH)*32)*K + (size_t)(KT)*64, shb + (BUF)*49152 + (HH)*4096 + tid*16)
#define OSTB(BUF,HH,KT) gld_lds16(qB + (size_t)((HH)*32)*K + (size_t)(KT)*64, shb + (BUF)*49152 + 32768 + (HH)*4096 + tid*16)
#define OVMW do { asm volatile("s_waitcnt vmcnt(4)" ::: "memory"); __builtin_amdgcn_sched_barrier(0); } while(0)
#define ORDA(BUF, MOFF, AA)                                                             \
    _Pragma("unroll") for (int mm = 0; mm < 4; ++mm){                                   \
      AA[mm][0] = *(const bf16x8*)(shb + (BUF)*49152 + rdA + ((MOFF)+mm)*2048 + sA0);   \
      AA[mm][1] = *(const bf16x8*)(shb + (BUF)*49152 + rdA + ((MOFF)+mm)*2048 + sA1);   \
    }
#define ORDB(BUF, BB)                                                                   \
    _Pragma("unroll") for (int nn = 0; nn < 4; ++nn){                                   \
      BB[nn][0] = *(const bf16x8*)(shb + (BUF)*49152 + rdB + nn*2048 + sA0);            \
      BB[nn][1] = *(const bf16x8*)(shb + (BUF)*49152 + rdB + nn*2048 + sA1);            \
    }
#define OMM(MOFF, AA, BB)                                                               \
    _Pragma("unroll") for (int mm = 0; mm < 4; ++mm)                                    \
      _Pragma("unroll") for (int nn = 0; nn < 4; ++nn)                                  \
        acc[(MOFF)+mm][nn] = __builtin_amdgcn_mfma_f32_16x16x32_bf16(AA[mm][0], BB[nn][0], acc[(MOFF)+mm][nn],0,0,0); \
    _Pragma("unroll") for (int mm = 0; mm < 4; ++mm)                                    \
      _Pragma("unroll") for (int nn = 0; nn < 4; ++nn)                                  \
        acc[(MOFF)+mm][nn] = __builtin_amdgcn_mfma_f32_16x16x32_bf16(AA[mm][1], BB[nn][1], acc[(MOFF)+mm][nn],0,0,0);

__global__ __launch_bounds__(256, 1)
void k_gemmo(const u16* __restrict__ A, const u16* __restrict__ Bm,
             float* __restrict__ C, int ldc, int K, int nkt){
  __shared__ char shb[98304];
  const int tid = threadIdx.x, ln = tid & 63, wid = tid >> 6;
  const int wm = wid >> 1, wn = wid & 1;
  const int lr = ln & 15, lg = ln >> 4;

  const int gx = gridDim.x;                 // 32 n-tiles (BN=128)
  const int mt = gridDim.y;                 // 8 m-tiles (BM=256)
  const int lin = blockIdx.y * gx + blockIdx.x;
  const int xcd = lin & 7, sub = lin >> 3;
  const int ncx = gx >> 3;
  const int n_local = sub / mt;
  const int m_idx   = sub % mt;
  const int m0 = m_idx << 8;                // BM = 256
  const int n0 = (xcd * ncx + n_local) << 7;// BN = 128

  const int srow = tid >> 3;
  const int slog = ((tid & 7) ^ (srow & 7)) * 8;
  const u16* qA = A + (size_t)(m0 + srow)*K + slog;
  const u16* qB = Bm + (size_t)(n0 + srow)*K + slog;

  const int sA0 = (lg ^ (ln & 7)) << 4;
  const int sA1 = ((4 + lg) ^ (ln & 7)) << 4;
  const u32 rdA = wm*16384 + lr*128;        // wave m-half = 128 rows
  const u32 rdB = 32768 + wn*8192 + lr*128; // wave n-half = 64 cols

  f32x4 acc[8][4] = {};

  // prologue
  #pragma unroll
  for (int hh = 0; hh < 8; ++hh) OSTA(0, hh, 0);
  #pragma unroll
  for (int hh = 0; hh < 4; ++hh) OSTB(0, hh, 0);
  #pragma unroll
  for (int hh = 0; hh < 4; ++hh) OSTB(1, hh, 1);
  OVMW;
  __builtin_amdgcn_s_barrier();
  __builtin_amdgcn_sched_barrier(0);

  const int nit = nkt >> 1;
  #pragma unroll 1
  for (int it = 0; it < nit; ++it){
    const int t1 = 2*it + 1;
    int t2 = 2*it + 2; if (t2 >= nkt) t2 = 0;
    int t3 = 2*it + 3; if (t3 >= nkt) t3 = 1;
    bf16x8 aa[4][2], bb0[4][2], bb1[4][2];
    { // P0
      ORDA(0, 0, aa) ORDB(0, bb0)
      #pragma unroll
      for (int hh = 0; hh < 8; ++hh) OSTA(1, hh, t1);
      __builtin_amdgcn_s_setprio(1);
      OMM(0, aa, bb0)
      ENDPH }
    { // P1
      ORDA(0, 4, aa)
      #pragma unroll
      for (int hh = 0; hh < 4; ++hh) OSTB(0, hh, t2);
      OVMW;
      __builtin_amdgcn_s_setprio(1);
      OMM(4, aa, bb0)
      ENDPH }
    { // P2
      ORDA(1, 0, aa) ORDB(1, bb1)
      #pragma unroll
      for (int hh = 0; hh < 8; ++hh) OSTA(0, hh, t2);
      __builtin_amdgcn_s_setprio(1);
      OMM(0, aa, bb1)
      ENDPH }
    { // P3
      ORDA(1, 4, aa)
      #pragma unroll
      for (int hh = 0; hh < 4; ++hh) OSTB(1, hh, t3);
      OVMW;
      __builtin_amdgcn_s_setprio(1);
      OMM(4, aa, bb1)
      ENDPH }
  }
  asm volatile("s_waitcnt vmcnt(0)" ::: "memory");

  const int crow = m0 + wm*128 + lg*4;
  const int ccol = n0 + wn*64 + lr;
  #pragma unroll
  for (int m = 0; m < 8; ++m)
    #pragma unroll
    for (int nn = 0; nn < 4; ++nn)
      #pragma unroll
      for (int r = 0; r < 4; ++r)
        C[(size_t)(crow + m*16 + r)*ldc + ccol + nn*16] = acc[m][nn][r];
}

// ---------------- conv1d(K=4) + SiLU + split (8ch/thread, u16x8 I/O) ----------------
__global__ __launch_bounds__(256)
void k_conv(const u16* __restrict__ proj16, const float* __restrict__ cw,
            const float* __restrict__ cb, u16* __restrict__ x16,
            u16* __restrict__ B16, u16* __restrict__ C16){
  const int ch0 = blockIdx.x*2048 + threadIdx.x*8;
  const int tbase = blockIdx.y*16;
  f32x4 w[8]; float bias[8];
  #pragma unroll
  for (int j = 0; j < 8; ++j){
    w[j] = *(const f32x4*)&cw[(size_t)(ch0+j)*4];
    bias[j] = cb[ch0+j];
  }
  const u16* pcol = proj16 + INTER_N + ch0;
  float p0[8], p1[8], p2[8];
  if (tbase >= 3){
    u16x8 v0 = *(const u16x8*)&pcol[(size_t)(tbase-3)*PROJ_N];
    u16x8 v1 = *(const u16x8*)&pcol[(size_t)(tbase-2)*PROJ_N];
    u16x8 v2 = *(const u16x8*)&pcol[(size_t)(tbase-1)*PROJ_N];
    #pragma unroll
    for (int j = 0; j < 8; ++j){ p0[j]=bf2f(v0[j]); p1[j]=bf2f(v1[j]); p2[j]=bf2f(v2[j]); }
  } else {
    #pragma unroll
    for (int j = 0; j < 8; ++j){ p0[j]=0.f; p1[j]=0.f; p2[j]=0.f; }
  }
  u16* xdst = (ch0 < INTER_N) ? x16 + ch0
            : (ch0 < INTER_N + 1024) ? B16 + (ch0 - INTER_N)
            : C16 + (ch0 - INTER_N - 1024);
  const int dstride = (ch0 < INTER_N) ? INTER_N : 1024;
  #pragma unroll 2
  for (int i = 0; i < 16; ++i){
    int t = tbase + i;
    u16x8 cv = *(const u16x8*)&pcol[(size_t)t*PROJ_N];
    u16x8 o;
    #pragma unroll
    for (int j = 0; j < 8; ++j){
      float cur = bf2f(cv[j]);
      float a = bias[j] + w[j][0]*p0[j] + w[j][1]*p1[j] + w[j][2]*p2[j] + w[j][3]*cur;
      o[j] = f2bf(a / (1.f + __expf(-a)));
      p0[j] = p1[j]; p1[j] = p2[j]; p2[j] = cur;
    }
    *(u16x8*)&xdst[(size_t)t*dstride] = o;
  }
}

// ---------------- SSD part A ----------------
__global__ __launch_bounds__(512)
void k_ssda(const u16* __restrict__ B16, const u16* __restrict__ x16,
            const float* __restrict__ dtv, const float* __restrict__ cum,
            const float* __restrict__ cumend, u16* __restrict__ SlocT){
  __shared__ u16 lBdT[128*136];
  __shared__ u16 lXdT[64*136];
  __shared__ float lDec[128], lDt[128];
  const int tid = threadIdx.x, wid = tid >> 6, ln = tid & 63;
  const int c = blockIdx.x >> 7, h = blockIdx.x & 127, g = h >> 4;
  if (tid < 128){
    int t = c*128 + tid;
    lDec[tid] = __expf(cumend[c*128 + h] - cum[(size_t)t*128 + h]);
    lDt[tid]  = dtv[(size_t)t*128 + h];
  }
  __syncthreads();
  for (int it = 0; it < 32; ++it){
    int idx = it*512 + tid;
    int q = idx >> 7, n = idx & 127;
    float bv = bf2f(B16[(size_t)(c*128 + q)*1024 + g*128 + n]) * lDec[q];
    lBdT[n*136 + q] = f2bf(bv);
  }
  for (int it = 0; it < 16; ++it){
    int idx = it*512 + tid;
    int q = idx >> 6, p = idx & 63;
    float xv = bf2f(x16[(size_t)(c*128 + q)*INTER_N + h*64 + p]) * lDt[q];
    lXdT[p*136 + q] = f2bf(xv);
  }
  __syncthreads();
  const int wr = wid >> 1, wc = wid & 1;
  const int kofs = (ln >> 4) << 3;
  f32x4 acc[2][2] = {};
  #pragma unroll
  for (int ks = 0; ks < 4; ++ks){
    bf16x8 a[2], b[2];
    #pragma unroll
    for (int m = 0; m < 2; ++m) a[m] = *(const bf16x8*)&lBdT[(wr*32 + m*16 + (ln & 15))*136 + ks*32 + kofs];
    #pragma unroll
    for (int n = 0; n < 2; ++n) b[n] = *(const bf16x8*)&lXdT[(wc*32 + n*16 + (ln & 15))*136 + ks*32 + kofs];
    #pragma unroll
    for (int m = 0; m < 2; ++m)
      #pragma unroll
      for (int n = 0; n < 2; ++n)
        acc[m][n] = __builtin_amdgcn_mfma_f32_16x16x32_bf16(a[m], b[n], acc[m][n], 0, 0, 0);
  }
  const size_t base = (size_t)(c*128 + h) * 8192;
  #pragma unroll
  for (int m = 0; m < 2; ++m)
    #pragma unroll
    for (int n = 0; n < 2; ++n){
      int p  = wc*32 + n*16 + (ln & 15);
      int nn = wr*32 + m*16 + ((ln >> 4) << 2);
      u16x4 o = { f2bf(acc[m][n][0]), f2bf(acc[m][n][1]), f2bf(acc[m][n][2]), f2bf(acc[m][n][3]) };
      *(u16x4*)&SlocT[base + (size_t)p*128 + nn] = o;
    }
}

// ---------------- chunk scan (u16x8) ----------------
__global__ __launch_bounds__(256)
void k_scan(const u16* __restrict__ SlocT, const float* __restrict__ dec,
            u16* __restrict__ SprevT){
  int idx = blockIdx.x*256 + threadIdx.x;
  int h = idx >> 10, p = (idx >> 4) & 63, n8 = (idx & 15)*8;
  float s[8] = {};
  for (int c = 0; c < NC_N; ++c){
    size_t off = (size_t)(c*128 + h)*8192 + (size_t)p*128 + n8;
    u16x8 o;
    #pragma unroll
    for (int j = 0; j < 8; ++j) o[j] = f2bf(s[j]);
    *(u16x8*)&SprevT[off] = o;
    u16x8 sl = *(const u16x8*)&SlocT[off];
    float d = dec[c*128 + h];
    #pragma unroll
    for (int j = 0; j < 8; ++j) s[j] = d*s[j] + bf2f(sl[j]);
  }
}

// ---------------- SSD part B ----------------
__global__ __launch_bounds__(512)
void k_ssdb(const u16* __restrict__ C16, const u16* __restrict__ B16g,
            const u16* __restrict__ x16, const float* __restrict__ dtv,
            const float* __restrict__ cum, const u16* __restrict__ SprevT,
            const u16* __restrict__ proj16, const float* __restrict__ Dres,
            u16* __restrict__ yg16){
  __shared__ u16 lC[128*136];
  __shared__ u16 lBP[128*136];
  __shared__ u16 lXdT[64*136];
  __shared__ float lCum[128], lDt[128];
  const int tid = threadIdx.x, wid = tid >> 6, ln = tid & 63;
  const int c = blockIdx.x >> 7, h = blockIdx.x & 127, g = h >> 4;
  if (tid < 128){
    int t = c*128 + tid;
    lCum[tid] = cum[(size_t)t*128 + h];
    lDt[tid]  = dtv[(size_t)t*128 + h];
  }
  __syncthreads();
  #pragma unroll
  for (int it = 0; it < 4; ++it){
    int idx = it*512 + tid;
    int q = idx >> 4, n8 = (idx & 15) << 3;
    size_t gi = (size_t)(c*128 + q)*1024 + g*128 + n8;
    *(u16x8*)&lC[q*136 + n8]  = *(const u16x8*)&C16[gi];
    *(u16x8*)&lBP[q*136 + n8] = *(const u16x8*)&B16g[gi];
  }
  for (int it = 0; it < 16; ++it){
    int idx = it*512 + tid;
    int q = idx >> 6, p = idx & 63;
    lXdT[p*136 + q] = f2bf(bf2f(x16[(size_t)(c*128 + q)*INTER_N + h*64 + p]) * lDt[q]);
  }
  __syncthreads();
  const int kofs = (ln >> 4) << 3;
  {
    const int wr = wid >> 2, wc = wid & 3;
    f32x4 cb[4][2] = {};
    #pragma unroll
    for (int ks = 0; ks < 4; ++ks){
      bf16x8 a[4], b[2];
      #pragma unroll
      for (int m = 0; m < 4; ++m) a[m] = *(const bf16x8*)&lC[(wr*64 + m*16 + (ln & 15))*136 + ks*32 + kofs];
      #pragma unroll
      for (int n = 0; n < 2; ++n) b[n] = *(const bf16x8*)&lBP[(wc*32 + n*16 + (ln & 15))*136 + ks*32 + kofs];
      #pragma unroll
      for (int m = 0; m < 4; ++m)
        #pragma unroll
        for (int n = 0; n < 2; ++n)
          cb[m][n] = __builtin_amdgcn_mfma_f32_16x16x32_bf16(a[m], b[n], cb[m][n], 0, 0, 0);
    }
    __syncthreads();
    #pragma unroll
    for (int m = 0; m < 4; ++m)
      #pragma unroll
      for (int n = 0; n < 2; ++n){
        int kcol = (wid & 3)*32 + n*16 + (ln & 15);
        float ck = lCum[kcol];
        #pragma unroll
        for (int r = 0; r < 4; ++r){
          int q = (wid >> 2)*64 + m*16 + ((ln >> 4) << 2) + r;
          float v = (kcol <= q) ? cb[m][n][r] * __expf(lCum[q] - ck) : 0.f;
          lBP[q*136 + kcol] = f2bf(v);
        }
      }
  }
  __syncthreads();
  const int yr = wid >> 1, yc = wid & 1;
  f32x4 y1[2][2] = {}, y2[2][2] = {};
  const size_t spbase = (size_t)(c*128 + h) * 8192;
  #pragma unroll
  for (int ks = 0; ks < 4; ++ks){
    bf16x8 ap[2], acf[2], bx[2], bs[2];
    #pragma unroll
    for (int m = 0; m < 2; ++m){
      int qr = yr*32 + m*16 + (ln & 15);
      ap[m]  = *(const bf16x8*)&lBP[qr*136 + ks*32 + kofs];
      acf[m] = *(const bf16x8*)&lC [qr*136 + ks*32 + kofs];
    }
    #pragma unroll
    for (int n = 0; n < 2; ++n){
      int p = yc*32 + n*16 + (ln & 15);
      bx[n] = *(const bf16x8*)&lXdT[p*136 + ks*32 + kofs];
      bs[n] = *(const bf16x8*)&SprevT[spbase + (size_t)p*128 + ks*32 + kofs];
    }
    #pragma unroll
    for (int m = 0; m < 2; ++m)
      #pragma unroll
      for (int n = 0; n < 2; ++n){
        y1[m][n] = __builtin_amdgcn_mfma_f32_16x16x32_bf16(ap[m],  bx[n], y1[m][n], 0, 0, 0);
        y2[m][n] = __builtin_amdgcn_mfma_f32_16x16x32_bf16(acf[m], bs[n], y2[m][n], 0, 0, 0);
      }
  }
  const float dh = Dres[h];
  #pragma unroll
  for (int m = 0; m < 2; ++m)
    #pragma unroll
    for (int r = 0; r < 4; ++r){
      int q = yr*32 + m*16 + ((ln >> 4) << 2) + r;
      float eq = __expf(lCum[q]);
      size_t t = (size_t)(c*128 + q);
      #pragma unroll
      for (int n = 0; n < 2; ++n){
        int p = yc*32 + n*16 + (ln & 15);
        int chn = h*64 + p;
        float xv = bf2f(x16[t*INTER_N + chn]);
        float zv = bf2f(proj16[t*PROJ_N + chn]);
        float yv = y1[m][n][r] + eq*y2[m][n][r] + dh*xv;
        float sg = zv / (1.f + __expf(-zv));
        yg16[t*INTER_N + chn] = f2bf(yv * sg);
      }
    }
}

// ---------------- gated RMSNorm over INTER (bf16 in, bf16 out) ----------------
__global__ __launch_bounds__(256)
void k_gnorm(const u16* __restrict__ yg, const float* __restrict__ gnw,
             u16* __restrict__ yn16){
  __shared__ float red[4];
  const int row = blockIdx.x, tid = threadIdx.x;
  const u16* rp = yg + (size_t)row * INTER_N;
  u16x8 v[4];
  float ss = 0.f;
  #pragma unroll
  for (int i = 0; i < 4; ++i){
    v[i] = *(const u16x8*)&rp[(size_t)(tid + i*256)*8];
    #pragma unroll
    for (int j = 0; j < 8; ++j){ float f = bf2f(v[i][j]); ss += f*f; }
  }
  #pragma unroll
  for (int o = 32; o > 0; o >>= 1) ss += __shfl_down(ss, o, 64);
  if ((tid & 63) == 0) red[tid >> 6] = ss;
  __syncthreads();
  float tot = (red[0] + red[1]) + (red[2] + red[3]);
  float sc = rsqrtf(tot / (float)INTER_N + 1e-5f);
  #pragma unroll
  for (int i = 0; i < 4; ++i){
    int c8 = (tid + i*256)*8;
    u16x8 o;
    #pragma unroll
    for (int j = 0; j < 8; ++j)
      o[j] = f2bf(bf2f(v[i][j]) * sc * gnw[c8 + j]);
    *(u16x8*)&yn16[(size_t)row*INTER_N + c8] = o;
  }
}

// =====================================================================================
extern "C" void kernel_launch(void* const* d_in, const int* in_sizes, int n_in,
                              void* d_out, int out_size, void* d_ws, size_t ws_size,
                              hipStream_t stream){
  (void)in_sizes; (void)n_in; (void)out_size;
  const float* hs_in     = (const float*)d_in[0];
  const float* res_in    = (const float*)d_in[1];
  const float* norm_w    = (const float*)d_in[2];
  const float* in_proj_w = (const float*)d_in[3];
  const float* conv_w    = (const float*)d_in[4];
  const float* conv_b    = (const float*)d_in[5];
  const float* A_log     = (const float*)d_in[6];
  const float* D_res     = (const float*)d_in[7];
  const float* dt_bias   = (const float*)d_in[8];
  const float* gn_w      = (const float*)d_in[9];
  const float* out_proj_w= (const float*)d_in[10];

  float* out0      = (float*)d_out;
  float* resid_out = out0 + (size_t)T_N * D_N;

  char* ws = (char*)d_ws;
  const size_t o_hs16   = 0;
  const size_t o_Win16  = 16777216;
  const size_t o_Wout16 = 168820736;
  const size_t o_proj   = 235929600;
  const size_t o_Wn     = 387973120;
  const size_t o_dtv    = 391118848;
  const size_t o_cum    = 392167424;
  const size_t o_cumend = 393216000;
  const size_t o_dec    = 393224192;
  const size_t o_rstd   = 393232384;
  const size_t o_x16    = 393240576;
  const size_t o_B16    = 426795008;
  const size_t o_C16    = 430989312;
  const size_t o_SlocT  = 435183616;
  const size_t o_SprevT = 468738048;
  const size_t o_yn16   = 502292480;
  const size_t WS_NEED  = 535846912;
  if (ws_size < WS_NEED) return;

  u16*   hs16   = (u16*)  (ws + o_hs16);
  u16*   Win16  = (u16*)  (ws + o_Win16);
  u16*   Wout16 = (u16*)  (ws + o_Wout16);
  u16*   proj16 = (u16*)  (ws + o_proj);
  float* Wn     = (float*)(ws + o_Wn);
  float* dtpart = (float*)(ws + o_proj);
  float* dta    = (float*)(ws + o_proj + (16u<<20));
  float* dtv    = (float*)(ws + o_dtv);
  float* cum    = (float*)(ws + o_cum);
  float* cumend = (float*)(ws + o_cumend);
  float* dec    = (float*)(ws + o_dec);
  float* rstd   = (float*)(ws + o_rstd);
  u16*   x16    = (u16*)  (ws + o_x16);
  u16*   B16    = (u16*)  (ws + o_B16);
  u16*   C16    = (u16*)  (ws + o_C16);
  u16*   SlocT  = (u16*)  (ws + o_SlocT);
  u16*   SprevT = (u16*)  (ws + o_SprevT);
  u16*   yn16   = (u16*)  (ws + o_yn16);
  u16*   yg16   = (u16*)  (ws + o_Win16);

  k_addnorm<<<T_N, 256, 0, stream>>>(hs_in, res_in, norm_w, resid_out, hs16, rstd);
  k_cvt2<<<6144, 256, 0, stream>>>(in_proj_w, Win16, (size_t)NGEMM_N * D_N / 4,
                                   out_proj_w, Wout16, (size_t)D_N * INTER_N / 4);
  k_wdt<<<128, 256, 0, stream>>>(in_proj_w, norm_w, Wn);
  k_dtgemm<<<1024, 256, 0, stream>>>(resid_out, Wn, dtpart);
  k_dtsum<<<1024, 256, 0, stream>>>(dtpart, rstd, dt_bias, A_log, dtv, dta);
  k_dtprep<<<NC_N, 128, 0, stream>>>(dta, cum, cumend, dec);
  // in_proj: BM=128, BN=192 (NF=6): grid 96 x 16 = 1536 = 3 exact rounds at 2 blocks/CU
  k_gemmw<6, u16><<<dim3(NGEMM_N/192, T_N/128), 256, 0, stream>>>(hs16, Win16, proj16, PROJ_N, D_N, D_N/64);
  k_conv<<<dim3(CONVD_N/2048, T_N/16), 256, 0, stream>>>(proj16, conv_w, conv_b, x16, B16, C16);
  k_ssda<<<NC_N * H_N, 512, 0, stream>>>(B16, x16, dtv, cum, cumend, SlocT);
  k_scan<<<512, 256, 0, stream>>>(SlocT, dec, SprevT);
  k_ssdb<<<NC_N * H_N, 512, 0, stream>>>(C16, B16, x16, dtv, cum, SprevT, proj16, D_res, yg16);
  k_gnorm<<<T_N, 256, 0, stream>>>(yg16, gn_w, yn16);
  // out_proj: BM=256, BN=128: grid 32 x 8 = 256 blocks = exactly one round at 1 block/CU
  k_gemmo<<<dim3(D_N/128, T_N/256), 256, 0, stream>>>(yn16, Wout16, out0, D_N, INTER_N, INTER_N/64);
}

// Round 16
// 801.372 us; speedup vs baseline: 1.0286x; 1.0251x over previous
//
#include <hip/hip_runtime.h>
#include <stdint.h>

typedef unsigned short u16;
typedef unsigned int   u32;
typedef float  f32x4  __attribute__((ext_vector_type(4)));
typedef __bf16 bf16x8 __attribute__((ext_vector_type(8)));
typedef u16    u16x4  __attribute__((ext_vector_type(4)));
typedef u16    u16x8  __attribute__((ext_vector_type(8)));

#define T_N     2048
#define D_N     4096
#define H_N     128
#define P_N     64
#define G_N     8
#define NS_N    128
#define INTER_N 8192
#define CONVD_N 10240
#define PROJ_N  18560
#define NGEMM_N 18432
#define NC_N    16

__device__ __forceinline__ float bf2f(u16 u){ u32 x = ((u32)u) << 16; return __builtin_bit_cast(float, x); }
__device__ __forceinline__ u16 f2bf(float f){
  u32 u = __builtin_bit_cast(u32, f);
  u += 0x7FFFu + ((u >> 16) & 1u);
  return (u16)(u >> 16);
}

__device__ __forceinline__ void gld_lds16(const void* g, void* lds){
  __builtin_amdgcn_global_load_lds(
      (const __attribute__((address_space(1))) void*)(uintptr_t)g,
      (__attribute__((address_space(3))) void*)(u32)(uintptr_t)lds,
      16, 0, 0);
}

// ---------------- add + RMSNorm ----------------
__global__ __launch_bounds__(256)
void k_addnorm(const float* __restrict__ hin, const float* __restrict__ rin,
               const float* __restrict__ nw, float* __restrict__ resid,
               u16* __restrict__ hs16, float* __restrict__ rstd){
  __shared__ float red[4];
  const int row = blockIdx.x, tid = threadIdx.x;
  const size_t rb = (size_t)row * D_N;
  f32x4 s[4];
  float ss = 0.f;
  #pragma unroll
  for (int i = 0; i < 4; ++i){
    int c4 = tid + i*256;
    f32x4 a = *(const f32x4*)&hin[rb + (size_t)c4*4];
    f32x4 b = *(const f32x4*)&rin[rb + (size_t)c4*4];
    s[i] = a + b;
    *(f32x4*)&resid[rb + (size_t)c4*4] = s[i];
    ss += s[i][0]*s[i][0] + s[i][1]*s[i][1] + s[i][2]*s[i][2] + s[i][3]*s[i][3];
  }
  #pragma unroll
  for (int o = 32; o > 0; o >>= 1) ss += __shfl_down(ss, o, 64);
  if ((tid & 63) == 0) red[tid >> 6] = ss;
  __syncthreads();
  float tot = (red[0] + red[1]) + (red[2] + red[3]);
  float rs = rsqrtf(tot / (float)D_N + 1e-5f);
  if (tid == 0) rstd[row] = rs;
  #pragma unroll
  for (int i = 0; i < 4; ++i){
    int c4 = tid + i*256;
    f32x4 w = *(const f32x4*)&nw[(size_t)c4*4];
    u16x4 o = { f2bf(s[i][0]*rs*w[0]), f2bf(s[i][1]*rs*w[1]),
                f2bf(s[i][2]*rs*w[2]), f2bf(s[i][3]*rs*w[3]) };
    *(u16x4*)&hs16[rb + (size_t)c4*4] = o;
  }
}

// ---------------- fp32 -> bf16 conversion (both weights in one launch) ----------------
__global__ void k_cvt2(const float* __restrict__ in1, u16* __restrict__ out1, size_t n4a,
                       const float* __restrict__ in2, u16* __restrict__ out2, size_t n4b){
  size_t i = (size_t)blockIdx.x * blockDim.x + threadIdx.x;
  size_t stride = (size_t)gridDim.x * blockDim.x;
  size_t tot = n4a + n4b;
  for (; i < tot; i += stride){
    const float* in = (i < n4a) ? in1 : in2;
    u16* out = (i < n4a) ? out1 : out2;
    size_t j = (i < n4a) ? i : i - n4a;
    f32x4 v = *(const f32x4*)&in[j*4];
    u16x4 o = { f2bf(v[0]), f2bf(v[1]), f2bf(v[2]), f2bf(v[3]) };
    *(u16x4*)&out[j*4] = o;
  }
}

// ---------------- Wn[d][h] = in_proj_w[18432+h][d] * norm_w[d]  (LDS transpose) ----------
__global__ __launch_bounds__(256)
void k_wdt(const float* __restrict__ W, const float* __restrict__ nw,
           float* __restrict__ Wn){
  __shared__ float lt[32][133];
  const int tid = threadIdx.x;
  const int d0 = blockIdx.x * 32;
  #pragma unroll
  for (int i = 0; i < 16; ++i){
    int h = i*8 + (tid >> 5);
    int d = tid & 31;
    lt[d][h] = W[(size_t)(INTER_N + CONVD_N + h)*D_N + d0 + d];
  }
  __syncthreads();
  #pragma unroll
  for (int i = 0; i < 4; ++i){
    int d = i*8 + (tid >> 5);
    int h4 = (tid & 31) * 4;
    float nwv = nw[d0 + d];
    f32x4 v = { lt[d][h4]*nwv, lt[d][h4+1]*nwv, lt[d][h4+2]*nwv, lt[d][h4+3]*nwv };
    *(f32x4*)&Wn[(size_t)(d0 + d)*128 + h4] = v;
  }
}

// ---------------- fp32 dt GEMM, split-K x8 (f32x4 LDS reads) ----------------
__global__ __launch_bounds__(256)
void k_dtgemm(const float* __restrict__ resid, const float* __restrict__ Wn,
              float* __restrict__ dtpart){
  __shared__ float lhs[16*128];
  const int tid = threadIdx.x;
  const int tb = blockIdx.x >> 3, ks = blockIdx.x & 7;
  const int t0 = tb * 16;
  const int k0 = ks * (D_N / 8);
  const int hcol = tid & 127, rh = tid >> 7;
  float acc[8] = {0,0,0,0,0,0,0,0};
  for (int kt = k0; kt < k0 + D_N/8; kt += 128){
    __syncthreads();
    #pragma unroll
    for (int it = 0; it < 2; ++it){
      int idx = it*256 + tid;
      int rr = idx >> 5, c4 = idx & 31;
      *(f32x4*)&lhs[rr*128 + c4*4] = *(const f32x4*)&resid[(size_t)(t0+rr)*D_N + kt + c4*4];
    }
    __syncthreads();
    #pragma unroll 4
    for (int kk4 = 0; kk4 < 32; ++kk4){
      f32x4 w4;
      #pragma unroll
      for (int j = 0; j < 4; ++j) w4[j] = Wn[(size_t)(kt + kk4*4 + j)*128 + hcol];
      #pragma unroll
      for (int j = 0; j < 8; ++j){
        f32x4 lv = *(const f32x4*)&lhs[(rh*8 + j)*128 + kk4*4];
        acc[j] += lv[0]*w4[0] + lv[1]*w4[1] + lv[2]*w4[2] + lv[3]*w4[3];
      }
    }
  }
  #pragma unroll
  for (int j = 0; j < 8; ++j){
    int t = t0 + rh*8 + j;
    dtpart[((size_t)ks*T_N + t)*128 + hcol] = acc[j];
  }
}

// ---------------- dt sum+softplus (fully parallel) ----------------
__global__ __launch_bounds__(256)
void k_dtsum(const float* __restrict__ dtpart, const float* __restrict__ rstd,
             const float* __restrict__ dt_bias, const float* __restrict__ A_log,
             float* __restrict__ dtv, float* __restrict__ dta){
  int idx = blockIdx.x*256 + threadIdx.x;       // T*128
  int t = idx >> 7, h = idx & 127;
  float s = 0.f;
  #pragma unroll
  for (int k = 0; k < 8; ++k) s += dtpart[((size_t)k*T_N + t)*128 + h];
  float x = s * rstd[t] + dt_bias[h];
  float dv = (x > 20.f) ? x : log1pf(expf(x));
  dtv[idx] = dv;
  dta[idx] = dv * (-expf(A_log[h]));
}

// ---------------- dt cumsum per chunk ------------------------
__global__ void k_dtprep(const float* __restrict__ dta, float* __restrict__ cum,
                         float* __restrict__ cumend, float* __restrict__ dec){
  int c = blockIdx.x, h = threadIdx.x;
  float cm = 0.f;
  for (int q = 0; q < 128; ++q){
    size_t i = (size_t)(c*128 + q)*128 + h;
    cm += dta[i];
    cum[i] = cm;
  }
  cumend[c*128 + h] = cm;
  dec[c*128 + h] = expf(cm);
}

// ========== 128 x (NF*32) merged-4-phase bf16 GEMM, wave tile 64 x (NF*16) ==========
// Characterized family ceiling: util ≈ 0.67 x (FLOP/LDS-byte) x 85/4060 -> NF=6: ~55%.
// 2 blocks/CU co-residency is load-bearing (1-block/CU variants regress ~20%).
#define STA(BUF,HH,KT) gld_lds16(pA + (size_t)((HH)*32)*K + (size_t)(KT)*64, shb + (BUF)*BSZ + (HH)*4096 + tid*16)
#define STB(BUF,HH,KT) gld_lds16(pB + (size_t)((HH)*32)*K + (size_t)(KT)*64, shb + (BUF)*BSZ + 16384 + (HH)*4096 + tid*16)
#define VMWN do { asm volatile("s_waitcnt vmcnt(%0)" :: "n"(NF) : "memory"); __builtin_amdgcn_sched_barrier(0); } while(0)
#define RDA4(BUF, MOFF)                                                                 \
    bf16x8 a0 = *(const bf16x8*)(shb + (BUF)*BSZ + rdA + (MOFF)*2048 + sA0);            \
    bf16x8 a1 = *(const bf16x8*)(shb + (BUF)*BSZ + rdA + (MOFF)*2048 + sA1);            \
    bf16x8 a2 = *(const bf16x8*)(shb + (BUF)*BSZ + rdA + ((MOFF)+1)*2048 + sA0);        \
    bf16x8 a3 = *(const bf16x8*)(shb + (BUF)*BSZ + rdA + ((MOFF)+1)*2048 + sA1);
#define RDBALL(BUF, BB)                                                                 \
    _Pragma("unroll") for (int nn = 0; nn < NF; ++nn){                                  \
      BB[nn][0] = *(const bf16x8*)(shb + (BUF)*BSZ + rdB + nn*2048 + sA0);              \
      BB[nn][1] = *(const bf16x8*)(shb + (BUF)*BSZ + rdB + nn*2048 + sA1);              \
    }
#define MM24(MOFF, BB)                                                                  \
    _Pragma("unroll") for (int nn = 0; nn < NF; ++nn)                                   \
      acc[(MOFF)+0][nn] = __builtin_amdgcn_mfma_f32_16x16x32_bf16(a0, BB[nn][0], acc[(MOFF)+0][nn],0,0,0); \
    _Pragma("unroll") for (int nn = 0; nn < NF; ++nn)                                   \
      acc[(MOFF)+1][nn] = __builtin_amdgcn_mfma_f32_16x16x32_bf16(a2, BB[nn][0], acc[(MOFF)+1][nn],0,0,0); \
    _Pragma("unroll") for (int nn = 0; nn < NF; ++nn)                                   \
      acc[(MOFF)+0][nn] = __builtin_amdgcn_mfma_f32_16x16x32_bf16(a1, BB[nn][1], acc[(MOFF)+0][nn],0,0,0); \
    _Pragma("unroll") for (int nn = 0; nn < NF; ++nn)                                   \
      acc[(MOFF)+1][nn] = __builtin_amdgcn_mfma_f32_16x16x32_bf16(a3, BB[nn][1], acc[(MOFF)+1][nn],0,0,0);
#define ENDPH                                                                           \
    __builtin_amdgcn_s_setprio(0);                                                      \
    __builtin_amdgcn_s_barrier();                                                       \
    __builtin_amdgcn_sched_barrier(0);

template<int NF, typename OT>
__global__ __launch_bounds__(256, 2)
void k_gemmw(const u16* __restrict__ A, const u16* __restrict__ Bm,
             OT* __restrict__ C, int ldc, int K, int nkt){
  constexpr int BSZ = 16384 + NF*4096;
  __shared__ char shb[2*BSZ];
  const int tid = threadIdx.x, ln = tid & 63, wid = tid >> 6;
  const int wm = wid >> 1, wn = wid & 1;
  const int lr = ln & 15, lg = ln >> 4;

  const int gx = gridDim.x;
  const int mt = gridDim.y;
  const int lin = blockIdx.y * gx + blockIdx.x;
  const int xcd = lin & 7, sub = lin >> 3;
  const int ncx = gx >> 3;
  const int n_local = sub / mt;
  const int m_idx   = sub % mt;
  const int m0 = m_idx << 7;
  const int n0 = (xcd * ncx + n_local) * (NF*32);

  const int srow = tid >> 3;
  const int slog = ((tid & 7) ^ (srow & 7)) * 8;
  const u16* pA = A + (size_t)(m0 + srow)*K + slog;
  const u16* pB = Bm + (size_t)(n0 + srow)*K + slog;

  const int sA0 = (lg ^ (ln & 7)) << 4;
  const int sA1 = ((4 + lg) ^ (ln & 7)) << 4;
  const u32 rdA = wm*8192 + lr*128;
  const u32 rdB = 16384 + wn*(NF*2048) + lr*128;

  f32x4 acc[4][NF] = {};

  STA(0,0,0); STA(0,1,0); STA(0,2,0); STA(0,3,0);
  #pragma unroll
  for (int hh = 0; hh < NF; ++hh) STB(0, hh, 0);
  #pragma unroll
  for (int hh = 0; hh < NF; ++hh) STB(1, hh, 1);
  VMWN;
  __builtin_amdgcn_s_barrier();
  __builtin_amdgcn_sched_barrier(0);

  const int nit = nkt >> 1;
  #pragma unroll 1
  for (int it = 0; it < nit; ++it){
    const int t1 = 2*it + 1;
    int t2 = 2*it + 2; if (t2 >= nkt) t2 = 0;
    int t3 = 2*it + 3; if (t3 >= nkt) t3 = 1;
    bf16x8 bb0[NF][2], bb1[NF][2];
    { RDA4(0, 0) RDBALL(0, bb0)
      STA(1,0,t1); STA(1,1,t1); STA(1,2,t1); STA(1,3,t1);
      __builtin_amdgcn_s_setprio(1);
      MM24(0, bb0)
      ENDPH }
    { RDA4(0, 2)
      #pragma unroll
      for (int hh = 0; hh < NF; ++hh) STB(0, hh, t2);
      VMWN;
      __builtin_amdgcn_s_setprio(1);
      MM24(2, bb0)
      ENDPH }
    { RDA4(1, 0) RDBALL(1, bb1)
      STA(0,0,t2); STA(0,1,t2); STA(0,2,t2); STA(0,3,t2);
      __builtin_amdgcn_s_setprio(1);
      MM24(0, bb1)
      ENDPH }
    { RDA4(1, 2)
      #pragma unroll
      for (int hh = 0; hh < NF; ++hh) STB(1, hh, t3);
      VMWN;
      __builtin_amdgcn_s_setprio(1);
      MM24(2, bb1)
      ENDPH }
  }
  asm volatile("s_waitcnt vmcnt(0)" ::: "memory");

  const int crow = m0 + wm*64 + lg*4;
  const int ccol = n0 + wn*(NF*16) + lr;
  #pragma unroll
  for (int m = 0; m < 4; ++m)
    #pragma unroll
    for (int nn = 0; nn < NF; ++nn)
      #pragma unroll
      for (int r = 0; r < 4; ++r){
        float v = acc[m][nn][r];
        if constexpr (__is_same(OT, float))
          C[(size_t)(crow + m*16 + r)*ldc + ccol + nn*16] = v;
        else
          C[(size_t)(crow + m*16 + r)*ldc + ccol + nn*16] = f2bf(v);
      }
}

// ---------------- conv1d(K=4) + SiLU + split (8ch/thread, u16x8 I/O) ----------------
__global__ __launch_bounds__(256)
void k_conv(const u16* __restrict__ proj16, const float* __restrict__ cw,
            const float* __restrict__ cb, u16* __restrict__ x16,
            u16* __restrict__ B16, u16* __restrict__ C16){
  const int ch0 = blockIdx.x*2048 + threadIdx.x*8;
  const int tbase = blockIdx.y*16;
  f32x4 w[8]; float bias[8];
  #pragma unroll
  for (int j = 0; j < 8; ++j){
    w[j] = *(const f32x4*)&cw[(size_t)(ch0+j)*4];
    bias[j] = cb[ch0+j];
  }
  const u16* pcol = proj16 + INTER_N + ch0;
  float p0[8], p1[8], p2[8];
  if (tbase >= 3){
    u16x8 v0 = *(const u16x8*)&pcol[(size_t)(tbase-3)*PROJ_N];
    u16x8 v1 = *(const u16x8*)&pcol[(size_t)(tbase-2)*PROJ_N];
    u16x8 v2 = *(const u16x8*)&pcol[(size_t)(tbase-1)*PROJ_N];
    #pragma unroll
    for (int j = 0; j < 8; ++j){ p0[j]=bf2f(v0[j]); p1[j]=bf2f(v1[j]); p2[j]=bf2f(v2[j]); }
  } else {
    #pragma unroll
    for (int j = 0; j < 8; ++j){ p0[j]=0.f; p1[j]=0.f; p2[j]=0.f; }
  }
  u16* xdst = (ch0 < INTER_N) ? x16 + ch0
            : (ch0 < INTER_N + 1024) ? B16 + (ch0 - INTER_N)
            : C16 + (ch0 - INTER_N - 1024);
  const int dstride = (ch0 < INTER_N) ? INTER_N : 1024;
  #pragma unroll 2
  for (int i = 0; i < 16; ++i){
    int t = tbase + i;
    u16x8 cv = *(const u16x8*)&pcol[(size_t)t*PROJ_N];
    u16x8 o;
    #pragma unroll
    for (int j = 0; j < 8; ++j){
      float cur = bf2f(cv[j]);
      float a = bias[j] + w[j][0]*p0[j] + w[j][1]*p1[j] + w[j][2]*p2[j] + w[j][3]*cur;
      o[j] = f2bf(a / (1.f + __expf(-a)));
      p0[j] = p1[j]; p1[j] = p2[j]; p2[j] = cur;
    }
    *(u16x8*)&xdst[(size_t)t*dstride] = o;
  }
}

// ---------------- SSD part A ----------------
__global__ __launch_bounds__(512)
void k_ssda(const u16* __restrict__ B16, const u16* __restrict__ x16,
            const float* __restrict__ dtv, const float* __restrict__ cum,
            const float* __restrict__ cumend, u16* __restrict__ SlocT){
  __shared__ u16 lBdT[128*136];
  __shared__ u16 lXdT[64*136];
  __shared__ float lDec[128], lDt[128];
  const int tid = threadIdx.x, wid = tid >> 6, ln = tid & 63;
  const int c = blockIdx.x >> 7, h = blockIdx.x & 127, g = h >> 4;
  if (tid < 128){
    int t = c*128 + tid;
    lDec[tid] = __expf(cumend[c*128 + h] - cum[(size_t)t*128 + h]);
    lDt[tid]  = dtv[(size_t)t*128 + h];
  }
  __syncthreads();
  for (int it = 0; it < 32; ++it){
    int idx = it*512 + tid;
    int q = idx >> 7, n = idx & 127;
    float bv = bf2f(B16[(size_t)(c*128 + q)*1024 + g*128 + n]) * lDec[q];
    lBdT[n*136 + q] = f2bf(bv);
  }
  for (int it = 0; it < 16; ++it){
    int idx = it*512 + tid;
    int q = idx >> 6, p = idx & 63;
    float xv = bf2f(x16[(size_t)(c*128 + q)*INTER_N + h*64 + p]) * lDt[q];
    lXdT[p*136 + q] = f2bf(xv);
  }
  __syncthreads();
  const int wr = wid >> 1, wc = wid & 1;
  const int kofs = (ln >> 4) << 3;
  f32x4 acc[2][2] = {};
  #pragma unroll
  for (int ks = 0; ks < 4; ++ks){
    bf16x8 a[2], b[2];
    #pragma unroll
    for (int m = 0; m < 2; ++m) a[m] = *(const bf16x8*)&lBdT[(wr*32 + m*16 + (ln & 15))*136 + ks*32 + kofs];
    #pragma unroll
    for (int n = 0; n < 2; ++n) b[n] = *(const bf16x8*)&lXdT[(wc*32 + n*16 + (ln & 15))*136 + ks*32 + kofs];
    #pragma unroll
    for (int m = 0; m < 2; ++m)
      #pragma unroll
      for (int n = 0; n < 2; ++n)
        acc[m][n] = __builtin_amdgcn_mfma_f32_16x16x32_bf16(a[m], b[n], acc[m][n], 0, 0, 0);
  }
  const size_t base = (size_t)(c*128 + h) * 8192;
  #pragma unroll
  for (int m = 0; m < 2; ++m)
    #pragma unroll
    for (int n = 0; n < 2; ++n){
      int p  = wc*32 + n*16 + (ln & 15);
      int nn = wr*32 + m*16 + ((ln >> 4) << 2);
      u16x4 o = { f2bf(acc[m][n][0]), f2bf(acc[m][n][1]), f2bf(acc[m][n][2]), f2bf(acc[m][n][3]) };
      *(u16x4*)&SlocT[base + (size_t)p*128 + nn] = o;
    }
}

// ---------------- chunk scan (u16x8) ----------------
__global__ __launch_bounds__(256)
void k_scan(const u16* __restrict__ SlocT, const float* __restrict__ dec,
            u16* __restrict__ SprevT){
  int idx = blockIdx.x*256 + threadIdx.x;
  int h = idx >> 10, p = (idx >> 4) & 63, n8 = (idx & 15)*8;
  float s[8] = {};
  for (int c = 0; c < NC_N; ++c){
    size_t off = (size_t)(c*128 + h)*8192 + (size_t)p*128 + n8;
    u16x8 o;
    #pragma unroll
    for (int j = 0; j < 8; ++j) o[j] = f2bf(s[j]);
    *(u16x8*)&SprevT[off] = o;
    u16x8 sl = *(const u16x8*)&SlocT[off];
    float d = dec[c*128 + h];
    #pragma unroll
    for (int j = 0; j < 8; ++j) s[j] = d*s[j] + bf2f(sl[j]);
  }
}

// ---------------- SSD part B ----------------
__global__ __launch_bounds__(512)
void k_ssdb(const u16* __restrict__ C16, const u16* __restrict__ B16g,
            const u16* __restrict__ x16, const float* __restrict__ dtv,
            const float* __restrict__ cum, const u16* __restrict__ SprevT,
            const u16* __restrict__ proj16, const float* __restrict__ Dres,
            u16* __restrict__ yg16){
  __shared__ u16 lC[128*136];
  __shared__ u16 lBP[128*136];
  __shared__ u16 lXdT[64*136];
  __shared__ float lCum[128], lDt[128];
  const int tid = threadIdx.x, wid = tid >> 6, ln = tid & 63;
  const int c = blockIdx.x >> 7, h = blockIdx.x & 127, g = h >> 4;
  if (tid < 128){
    int t = c*128 + tid;
    lCum[tid] = cum[(size_t)t*128 + h];
    lDt[tid]  = dtv[(size_t)t*128 + h];
  }
  __syncthreads();
  #pragma unroll
  for (int it = 0; it < 4; ++it){
    int idx = it*512 + tid;
    int q = idx >> 4, n8 = (idx & 15) << 3;
    size_t gi = (size_t)(c*128 + q)*1024 + g*128 + n8;
    *(u16x8*)&lC[q*136 + n8]  = *(const u16x8*)&C16[gi];
    *(u16x8*)&lBP[q*136 + n8] = *(const u16x8*)&B16g[gi];
  }
  for (int it = 0; it < 16; ++it){
    int idx = it*512 + tid;
    int q = idx >> 6, p = idx & 63;
    lXdT[p*136 + q] = f2bf(bf2f(x16[(size_t)(c*128 + q)*INTER_N + h*64 + p]) * lDt[q]);
  }
  __syncthreads();
  const int kofs = (ln >> 4) << 3;
  {
    const int wr = wid >> 2, wc = wid & 3;
    f32x4 cb[4][2] = {};
    #pragma unroll
    for (int ks = 0; ks < 4; ++ks){
      bf16x8 a[4], b[2];
      #pragma unroll
      for (int m = 0; m < 4; ++m) a[m] = *(const bf16x8*)&lC[(wr*64 + m*16 + (ln & 15))*136 + ks*32 + kofs];
      #pragma unroll
      for (int n = 0; n < 2; ++n) b[n] = *(const bf16x8*)&lBP[(wc*32 + n*16 + (ln & 15))*136 + ks*32 + kofs];
      #pragma unroll
      for (int m = 0; m < 4; ++m)
        #pragma unroll
        for (int n = 0; n < 2; ++n)
          cb[m][n] = __builtin_amdgcn_mfma_f32_16x16x32_bf16(a[m], b[n], cb[m][n], 0, 0, 0);
    }
    __syncthreads();
    #pragma unroll
    for (int m = 0; m < 4; ++m)
      #pragma unroll
      for (int n = 0; n < 2; ++n){
        int kcol = (wid & 3)*32 + n*16 + (ln & 15);
        float ck = lCum[kcol];
        #pragma unroll
        for (int r = 0; r < 4; ++r){
          int q = (wid >> 2)*64 + m*16 + ((ln >> 4) << 2) + r;
          float v = (kcol <= q) ? cb[m][n][r] * __expf(lCum[q] - ck) : 0.f;
          lBP[q*136 + kcol] = f2bf(v);
        }
      }
  }
  __syncthreads();
  const int yr = wid >> 1, yc = wid & 1;
  f32x4 y1[2][2] = {}, y2[2][2] = {};
  const size_t spbase = (size_t)(c*128 + h) * 8192;
  #pragma unroll
  for (int ks = 0; ks < 4; ++ks){
    bf16x8 ap[2], acf[2], bx[2], bs[2];
    #pragma unroll
    for (int m = 0; m < 2; ++m){
      int qr = yr*32 + m*16 + (ln & 15);
      ap[m]  = *(const bf16x8*)&lBP[qr*136 + ks*32 + kofs];
      acf[m] = *(const bf16x8*)&lC [qr*136 + ks*32 + kofs];
    }
    #pragma unroll
    for (int n = 0; n < 2; ++n){
      int p = yc*32 + n*16 + (ln & 15);
      bx[n] = *(const bf16x8*)&lXdT[p*136 + ks*32 + kofs];
      bs[n] = *(const bf16x8*)&SprevT[spbase + (size_t)p*128 + ks*32 + kofs];
    }
    #pragma unroll
    for (int m = 0; m < 2; ++m)
      #pragma unroll
      for (int n = 0; n < 2; ++n){
        y1[m][n] = __builtin_amdgcn_mfma_f32_16x16x32_bf16(ap[m],  bx[n], y1[m][n], 0, 0, 0);
        y2[m][n] = __builtin_amdgcn_mfma_f32_16x16x32_bf16(acf[m], bs[n], y2[m][n], 0, 0, 0);
      }
  }
  const float dh = Dres[h];
  #pragma unroll
  for (int m = 0; m < 2; ++m)
    #pragma unroll
    for (int r = 0; r < 4; ++r){
      int q = yr*32 + m*16 + ((ln >> 4) << 2) + r;
      float eq = __expf(lCum[q]);
      size_t t = (size_t)(c*128 + q);
      #pragma unroll
      for (int n = 0; n < 2; ++n){
        int p = yc*32 + n*16 + (ln & 15);
        int chn = h*64 + p;
        float xv = bf2f(x16[t*INTER_N + chn]);
        float zv = bf2f(proj16[t*PROJ_N + chn]);
        float yv = y1[m][n][r] + eq*y2[m][n][r] + dh*xv;
        float sg = zv / (1.f + __expf(-zv));
        yg16[t*INTER_N + chn] = f2bf(yv * sg);
      }
    }
}

// ---------------- gated RMSNorm over INTER (bf16 in, bf16 out) ----------------
__global__ __launch_bounds__(256)
void k_gnorm(const u16* __restrict__ yg, const float* __restrict__ gnw,
             u16* __restrict__ yn16){
  __shared__ float red[4];
  const int row = blockIdx.x, tid = threadIdx.x;
  const u16* rp = yg + (size_t)row * INTER_N;
  u16x8 v[4];
  float ss = 0.f;
  #pragma unroll
  for (int i = 0; i < 4; ++i){
    v[i] = *(const u16x8*)&rp[(size_t)(tid + i*256)*8];
    #pragma unroll
    for (int j = 0; j < 8; ++j){ float f = bf2f(v[i][j]); ss += f*f; }
  }
  #pragma unroll
  for (int o = 32; o > 0; o >>= 1) ss += __shfl_down(ss, o, 64);
  if ((tid & 63) == 0) red[tid >> 6] = ss;
  __syncthreads();
  float tot = (red[0] + red[1]) + (red[2] + red[3]);
  float sc = rsqrtf(tot / (float)INTER_N + 1e-5f);
  #pragma unroll
  for (int i = 0; i < 4; ++i){
    int c8 = (tid + i*256)*8;
    u16x8 o;
    #pragma unroll
    for (int j = 0; j < 8; ++j)
      o[j] = f2bf(bf2f(v[i][j]) * sc * gnw[c8 + j]);
    *(u16x8*)&yn16[(size_t)row*INTER_N + c8] = o;
  }
}

// =====================================================================================
extern "C" void kernel_launch(void* const* d_in, const int* in_sizes, int n_in,
                              void* d_out, int out_size, void* d_ws, size_t ws_size,
                              hipStream_t stream){
  (void)in_sizes; (void)n_in; (void)out_size;
  const float* hs_in     = (const float*)d_in[0];
  const float* res_in    = (const float*)d_in[1];
  const float* norm_w    = (const float*)d_in[2];
  const float* in_proj_w = (const float*)d_in[3];
  const float* conv_w    = (const float*)d_in[4];
  const float* conv_b    = (const float*)d_in[5];
  const float* A_log     = (const float*)d_in[6];
  const float* D_res     = (const float*)d_in[7];
  const float* dt_bias   = (const float*)d_in[8];
  const float* gn_w      = (const float*)d_in[9];
  const float* out_proj_w= (const float*)d_in[10];

  float* out0      = (float*)d_out;
  float* resid_out = out0 + (size_t)T_N * D_N;

  char* ws = (char*)d_ws;
  const size_t o_hs16   = 0;
  const size_t o_Win16  = 16777216;
  const size_t o_Wout16 = 168820736;
  const size_t o_proj   = 235929600;
  const size_t o_Wn     = 387973120;
  const size_t o_dtv    = 391118848;
  const size_t o_cum    = 392167424;
  const size_t o_cumend = 393216000;
  const size_t o_dec    = 393224192;
  const size_t o_rstd   = 393232384;
  const size_t o_x16    = 393240576;
  const size_t o_B16    = 426795008;
  const size_t o_C16    = 430989312;
  const size_t o_SlocT  = 435183616;
  const size_t o_SprevT = 468738048;
  const size_t o_yn16   = 502292480;
  const size_t WS_NEED  = 535846912;
  if (ws_size < WS_NEED) return;

  u16*   hs16   = (u16*)  (ws + o_hs16);
  u16*   Win16  = (u16*)  (ws + o_Win16);
  u16*   Wout16 = (u16*)  (ws + o_Wout16);
  u16*   proj16 = (u16*)  (ws + o_proj);
  float* Wn     = (float*)(ws + o_Wn);
  float* dtpart = (float*)(ws + o_proj);
  float* dta    = (float*)(ws + o_proj + (16u<<20));
  float* dtv    = (float*)(ws + o_dtv);
  float* cum    = (float*)(ws + o_cum);
  float* cumend = (float*)(ws + o_cumend);
  float* dec    = (float*)(ws + o_dec);
  float* rstd   = (float*)(ws + o_rstd);
  u16*   x16    = (u16*)  (ws + o_x16);
  u16*   B16    = (u16*)  (ws + o_B16);
  u16*   C16    = (u16*)  (ws + o_C16);
  u16*   SlocT  = (u16*)  (ws + o_SlocT);
  u16*   SprevT = (u16*)  (ws + o_SprevT);
  u16*   yn16   = (u16*)  (ws + o_yn16);
  u16*   yg16   = (u16*)  (ws + o_Win16);

  k_addnorm<<<T_N, 256, 0, stream>>>(hs_in, res_in, norm_w, resid_out, hs16, rstd);
  k_cvt2<<<6144, 256, 0, stream>>>(in_proj_w, Win16, (size_t)NGEMM_N * D_N / 4,
                                   out_proj_w, Wout16, (size_t)D_N * INTER_N / 4);
  k_wdt<<<128, 256, 0, stream>>>(in_proj_w, norm_w, Wn);
  k_dtgemm<<<1024, 256, 0, stream>>>(resid_out, Wn, dtpart);
  k_dtsum<<<1024, 256, 0, stream>>>(dtpart, rstd, dt_bias, A_log, dtv, dta);
  k_dtprep<<<NC_N, 128, 0, stream>>>(dta, cum, cumend, dec);
  // in_proj: BM=128, BN=192 (NF=6): grid 96 x 16 = 1536 = 3 exact rounds at 2 blocks/CU
  k_gemmw<6, u16><<<dim3(NGEMM_N/192, T_N/128), 256, 0, stream>>>(hs16, Win16, proj16, PROJ_N, D_N, D_N/64);
  k_conv<<<dim3(CONVD_N/2048, T_N/16), 256, 0, stream>>>(proj16, conv_w, conv_b, x16, B16, C16);
  k_ssda<<<NC_N * H_N, 512, 0, stream>>>(B16, x16, dtv, cum, cumend, SlocT);
  k_scan<<<512, 256, 0, stream>>>(SlocT, dec, SprevT);
  k_ssdb<<<NC_N * H_N, 512, 0, stream>>>(C16, B16, x16, dtv, cum, SprevT, proj16, D_res, yg16);
  k_gnorm<<<T_N, 256, 0, stream>>>(yg16, gn_w, yn16);
  // out_proj: BM=128, BN=128 (NF=4): grid 32 x 16 = 512 = ONE exact round at 2 blocks/CU
  k_gemmw<4, float><<<dim3(D_N/128, T_N/128), 256, 0, stream>>>(yn16, Wout16, out0, D_N, INTER_N, INTER_N/64);
}